// Round 10
// baseline (632.971 us; speedup 1.0000x reference)
//
#include <hip/hip_runtime.h>
#include <math.h>

// ws layout (float offsets)
#define SB_OFF   0          // tagged strips [2][512][1152] = 1179648 floats (4.72 MB)
#define E_OFF    1179648    // e [128][2048] = 262144 floats
// total 1441792 floats = 5.77 MB
// strip record (1152 floats/tile), all entries (payload,tag) f2 pairs:
//   HT[4][32]@0  HB[4][32]@256  VL[32][4]@512  VR[32][4]@768
//   CTL[4][4]@1024  CTR@1056  CBL@1088  CBR@1120

__device__ __forceinline__ float fast_tanh(float x) {
  x = fminf(fmaxf(x, -15.f), 15.f);
  float ex = __expf(2.f * x);
  return __fdividef(ex - 1.f, ex + 1.f);
}

// octet (8-lane) sum via DPP — pure VALU, off the LDS pipe.
template <int CTRL>
__device__ __forceinline__ float dpp_add(float v) {
  int x = __builtin_amdgcn_update_dpp(0, __float_as_int(v), CTRL, 0xF, 0xF, true);
  return v + __int_as_float(x);
}

// Cross-XCD coherent path: relaxed AGENT-scope atomics at the coherent point.
__device__ __forceinline__ float2 aload_f2(const float* p) {
  unsigned long long v = __hip_atomic_load((const unsigned long long*)p,
                                           __ATOMIC_RELAXED, __HIP_MEMORY_SCOPE_AGENT);
  float2 r;
  r.x = __uint_as_float((unsigned)v);
  r.y = __uint_as_float((unsigned)(v >> 32));
  return r;
}
__device__ __forceinline__ void astore_f2(float* p, float a, float b) {
  unsigned long long v =
      ((unsigned long long)__float_as_uint(b) << 32) | (unsigned long long)__float_as_uint(a);
  __hip_atomic_store((unsigned long long*)p, v, __ATOMIC_RELAXED, __HIP_MEMORY_SCOPE_AGENT);
}

// ---------------- K0: embed e = (X@W^T)*mask_coarse; init out = bias
__global__ __launch_bounds__(256) void prep_kernel(
    const float* __restrict__ X, const float* __restrict__ W_embed,
    const float* __restrict__ mask_coarse, const float* __restrict__ b_out,
    float* __restrict__ ws, float* __restrict__ out)
{
  const int tid = threadIdx.x, bid = blockIdx.x;  // grid = 256
  float* eb = ws + E_OFF;

  // out = bias (scan_kernel atomicAdds channel contributions on top)
  {
    int i0 = bid * 512 + tid * 2;
    out[i0]     = b_out[(i0 >> 6) & 15];
    out[i0 + 1] = b_out[((i0 + 1) >> 6) & 15];
  }

  const int o  = bid * 8 + (tid >> 5);     // 2048 output rows
  const int t0 = (tid & 31) * 4;           // 4 t's per thread
  const float4* Wf4 = (const float4*)W_embed + (size_t)o * 128;
  const float4* Xf4 = (const float4*)X;
  float acc[4] = {0.f, 0.f, 0.f, 0.f};
  for (int k4 = 0; k4 < 128; ++k4) {
    float4 wv = Wf4[k4];
#pragma unroll
    for (int tt = 0; tt < 4; ++tt) {
      float4 xv = Xf4[(size_t)(t0 + tt) * 128 + k4];
      acc[tt] = fmaf(wv.x, xv.x, fmaf(wv.y, xv.y, fmaf(wv.z, xv.z, fmaf(wv.w, xv.w, acc[tt]))));
    }
  }
  float mc = mask_coarse[o & 255];
#pragma unroll
  for (int tt = 0; tt < 4; ++tt)
    eb[(size_t)(t0 + tt) * 2048 + o] = acc[tt] * mc;
}

// ---------------- K1: persistent scan. 512 blocks x 256 threads (2 blocks/CU).
// 8 ch x (8x8 tiles of 32x32); 1 float4-group per thread. State in LDS;
// boundary via (payload,tag) atomics. Tile == readout patch -> atomicAdd out.
__global__ __launch_bounds__(256, 2) void scan_kernel(
    const float* __restrict__ mask_fine, const float* __restrict__ W_deconv,
    const float* __restrict__ w1, const float* __restrict__ w2,
    const float* __restrict__ w_out, float* __restrict__ ws,
    float* __restrict__ out)
{
  __shared__ float zin[40 * 44];      // persistent tile + 4-halo (stride 44)
  __shared__ float rowbuf[32 * 17];   // per-row readout partials

  const int tid  = threadIdx.x;       // 0..255
  const int bid  = blockIdx.x;        // 0..511
  const int ch   = bid >> 6;
  const int tile = bid & 63;
  const int tI = tile >> 3, tJ = tile & 7;   // 8 x 8 tile grid
  const int r0 = tI << 5, c0 = tJ << 5;
  const int row = tid >> 3;           // 0..31
  const int cg  = tid & 7;
  const int lc  = cg << 2;

  float* Zb = ws + SB_OFF;
  const float* eb = ws + E_OFF;
  const int myoff = (ch * 64 + tile) * 1152;

  // ---- per-thread fixed constants
  const int a16 = (r0 + row) & 15;
  const int b16 = lc & 15;            // c0,lc multiples of 32/4; (c0+lc)&15 == lc&15
  const int i0  = (r0 + row) >> 4;
  const int jj  = (c0 + lc) >> 4;
  float4 wd[8];
#pragma unroll
  for (int c = 0; c < 8; ++c)
    wd[c] = *(const float4*)&W_deconv[(((c * 8 + ch) * 16) + a16) * 16 + b16];
  float4 mf = *(const float4*)&mask_fine[(size_t)(r0 + row) * 256 + c0 + lc];
  float4 wo[16];
#pragma unroll
  for (int oc = 0; oc < 16; ++oc)
    wo[oc] = *(const float4*)&w_out[(((oc * 8 + ch) * 32) + row) * 32 + lc];
  float w1s[9], w2s[25];
#pragma unroll
  for (int k = 0; k < 9; ++k)
    w1s[k] = __uint_as_float(__builtin_amdgcn_readfirstlane(__float_as_uint(w1[ch * 9 + k])));
#pragma unroll
  for (int k = 0; k < 25; ++k)
    w2s[k] = __uint_as_float(__builtin_amdgcn_readfirstlane(__float_as_uint(w2[ch * 25 + k])));

  // ---- fixed halo-read assignments: 576 (payload,tag) words; 2-3 per thread
  int rd_off[3] = {0, 0, 0}, rd_dst[3] = {0, 0, 0};
  {
    int n = 0;
    auto setup = [&](int u) {
      int di = 0, dj = 0, off = 0, dst = 0;
      if (u < 128) {            // top rows 0..3, cols 4..35   <- U.HB
        int r = u >> 5, c = u & 31;
        di = -1; dj = 0; off = 256 + 2 * u; dst = r * 44 + 4 + c;
      } else if (u < 256) {     // bottom rows 36..39          <- D.HT
        int v = u - 128;
        di = 1; dj = 0; off = 2 * v; dst = (36 + (v >> 5)) * 44 + 4 + (v & 31);
      } else if (u < 384) {     // left rows 4..35, cols 0..3  <- L.VR
        int v = u - 256;
        di = 0; dj = -1; off = 768 + 2 * v; dst = (4 + (v >> 2)) * 44 + (v & 3);
      } else if (u < 512) {     // right rows 4..35, cols 36..39 <- R.VL
        int v = u - 384;
        di = 0; dj = 1; off = 512 + 2 * v; dst = (4 + (v >> 2)) * 44 + 36 + (v & 3);
      } else {                  // corners, 16 words each
        int v = u - 512; int corner = v >> 4, k = v & 15, r = k >> 2, c = k & 3;
        if (corner == 0)      { di = -1; dj = -1; off = 1120 + 2 * k; dst = r * 44 + c; }
        else if (corner == 1) { di = -1; dj = 1;  off = 1088 + 2 * k; dst = r * 44 + 36 + c; }
        else if (corner == 2) { di = 1;  dj = -1; off = 1056 + 2 * k; dst = (36 + r) * 44 + c; }
        else                  { di = 1;  dj = 1;  off = 1024 + 2 * k; dst = (36 + r) * 44 + 36 + c; }
      }
      int nI = (tI + di) & 7, nJ = (tJ + dj) & 7;
      rd_off[n] = (ch * 64 + nI * 8 + nJ) * 1152 + off;
      rd_dst[n] = dst;
      ++n;
    };
    setup(tid);
    setup(tid + 256);
    if (tid < 64) setup(tid + 512);
  }
  const bool has3 = (tid < 64);

  // init persistent state (Z0 = 0, incl. halo)
  for (int k = tid; k < 40 * 44; k += 256) zin[k] = 0.f;
  __syncthreads();

  for (int t = 0; t < 128; ++t) {
    float* sb = Zb + (size_t)((t + 1) & 1) * 589824;   // tagged strips for Z_{t+1}

    // input-path e values (read-only, L2-resident)
    float ev[8];
#pragma unroll
    for (int c = 0; c < 8; ++c)
      ev[c] = eb[(size_t)t * 2048 + c * 256 + i0 * 16 + jj];

    // ---- compute Z_{t+1} for this thread's 4 px (reads zin = Z_t incl halo)
    float c1a[4] = {0, 0, 0, 0}, c2a[4] = {0, 0, 0, 0};
    {
      float w[12];
      auto load_row = [&](int zr) {
        float4 A  = *(const float4*)&zin[zr * 44 + lc];
        float4 B  = *(const float4*)&zin[zr * 44 + lc + 4];
        float4 Cq = *(const float4*)&zin[zr * 44 + lc + 8];
        w[0]=A.x; w[1]=A.y; w[2]=A.z; w[3]=A.w;
        w[4]=B.x; w[5]=B.y; w[6]=B.z; w[7]=B.w;
        w[8]=Cq.x; w[9]=Cq.y; w[10]=Cq.z; w[11]=Cq.w;
      };
      auto k2row = [&](int a) {
#pragma unroll
        for (int j = 0; j < 4; ++j)
#pragma unroll
          for (int b = 0; b < 5; ++b)
            c2a[j] = fmaf(w[j + 2 * b], w2s[a * 5 + b], c2a[j]);
      };
      auto k1row = [&](int a) {
#pragma unroll
        for (int j = 0; j < 4; ++j)
#pragma unroll
          for (int b = 0; b < 3; ++b)
            c1a[j] = fmaf(w[j + 3 + b], w1s[a * 3 + b], c1a[j]);
      };
      load_row(row + 0); k2row(0);
      load_row(row + 2); k2row(1);
      load_row(row + 3); k1row(0);
      load_row(row + 4); k1row(1); k2row(2);
      load_row(row + 5); k1row(2);
      load_row(row + 6); k2row(3);
      load_row(row + 8); k2row(4);
    }
    float zv[4];
    {
      const float* mfp = (const float*)&mf;
#pragma unroll
      for (int j = 0; j < 4; ++j) {
        float u = 0.f;
#pragma unroll
        for (int c = 0; c < 8; ++c)
          u = fmaf(ev[c], ((const float*)&wd[c])[j], u);
        float val = fmaf(0.9f, c1a[j], fmaf(0.1f, c2a[j], mfp[j] * u));
        zv[j] = fast_tanh(val);
      }
    }

    // ---- publish tagged boundary words NOW (before barrier A)
    if (t < 127) {
      float* myrec = sb + myoff;
      const float tagf = __uint_as_float((unsigned)(t + 1));
      if (row < 4) {
#pragma unroll
        for (int j = 0; j < 4; ++j)
          astore_f2(myrec + 2 * (row * 32 + lc + j), zv[j], tagf);              // HT
      }
      if (row >= 28) {
#pragma unroll
        for (int j = 0; j < 4; ++j)
          astore_f2(myrec + 256 + 2 * ((row - 28) * 32 + lc + j), zv[j], tagf); // HB
      }
      if (lc == 0) {
#pragma unroll
        for (int j = 0; j < 4; ++j)
          astore_f2(myrec + 512 + 2 * (row * 4 + j), zv[j], tagf);              // VL
      }
      if (lc == 28) {
#pragma unroll
        for (int j = 0; j < 4; ++j)
          astore_f2(myrec + 768 + 2 * (row * 4 + j), zv[j], tagf);              // VR
      }
      if (row < 4 && lc == 0) {
#pragma unroll
        for (int j = 0; j < 4; ++j)
          astore_f2(myrec + 1024 + 2 * (row * 4 + j), zv[j], tagf);             // CTL
      }
      if (row < 4 && lc == 28) {
#pragma unroll
        for (int j = 0; j < 4; ++j)
          astore_f2(myrec + 1056 + 2 * (row * 4 + j), zv[j], tagf);             // CTR
      }
      if (row >= 28 && lc == 0) {
#pragma unroll
        for (int j = 0; j < 4; ++j)
          astore_f2(myrec + 1088 + 2 * ((row - 28) * 4 + j), zv[j], tagf);      // CBL
      }
      if (row >= 28 && lc == 28) {
#pragma unroll
        for (int j = 0; j < 4; ++j)
          astore_f2(myrec + 1120 + 2 * ((row - 28) * 4 + j), zv[j], tagf);      // CBR
      }
    }

    float racc[16];
#pragma unroll
    for (int oc = 0; oc < 16; ++oc) {
      const float* wop = (const float*)&wo[oc];
      racc[oc] = fmaf(zv[0], wop[0], fmaf(zv[1], wop[1], fmaf(zv[2], wop[2], zv[3] * wop[3])));
    }

    __syncthreads();  // A: all reads of Z_t from zin complete

    // ---- commit interior to LDS
    *(float4*)&zin[(4 + row) * 44 + 4 + lc] = make_float4(zv[0], zv[1], zv[2], zv[3]);

    // ---- readout reduction stage 1: octet sum via DPP (VALU pipe)
#pragma unroll
    for (int k = 0; k < 16; ++k) {
      racc[k] = dpp_add<0xB1>(racc[k]);    // + xor1
      racc[k] = dpp_add<0x4E>(racc[k]);    // + xor2
      racc[k] = dpp_add<0x141>(racc[k]);   // + cross-quad (row_half_mirror)
    }
    rowbuf[row * 17 + (cg << 1)]     = racc[cg << 1];
    rowbuf[row * 17 + (cg << 1) + 1] = racc[(cg << 1) + 1];

    // ---- halo: poll the tagged words directly
    if (t < 127) {
      const unsigned tg = (unsigned)(t + 1);
#pragma unroll
      for (int q = 0; q < 2; ++q) {
        const float* p = sb + rd_off[q];
        float2 v2; int spins = 0;
        do { v2 = aload_f2(p);
             if (__float_as_uint(v2.y) == tg) break;
             __builtin_amdgcn_s_sleep(1);
        } while (++spins < (1 << 18));   // fail loud (wrong), never hang
        zin[rd_dst[q]] = v2.x;
      }
      if (has3) {
        const float* p = sb + rd_off[2];
        float2 v2; int spins = 0;
        do { v2 = aload_f2(p);
             if (__float_as_uint(v2.y) == tg) break;
             __builtin_amdgcn_s_sleep(1);
        } while (++spins < (1 << 18));
        zin[rd_dst[2]] = v2.x;
      }
    }

    __syncthreads();  // B: zin (interior + halo) and rowbuf complete

    // ---- stage 2: 16 threads fold 32 rows -> atomicAdd into out[t]
    if (tid < 16) {
      float s = 0.f;
#pragma unroll
      for (int r = 0; r < 32; ++r) s += rowbuf[r * 17 + tid];
      atomicAdd(&out[t * 1024 + tid * 64 + tI * 8 + tJ], s);
    }
  }
}

extern "C" void kernel_launch(void* const* d_in, const int* in_sizes, int n_in,
                              void* d_out, int out_size, void* d_ws, size_t ws_size,
                              hipStream_t stream) {
  const float* X           = (const float*)d_in[0];
  const float* W_embed     = (const float*)d_in[1];
  const float* mask_coarse = (const float*)d_in[2];
  const float* mask_fine   = (const float*)d_in[3];
  const float* W_deconv    = (const float*)d_in[4];
  const float* w1          = (const float*)d_in[5];
  const float* w2          = (const float*)d_in[6];
  const float* w_out       = (const float*)d_in[7];
  const float* b_out       = (const float*)d_in[8];
  float* ws  = (float*)d_ws;
  float* out = (float*)d_out;

  prep_kernel<<<dim3(256), dim3(256), 0, stream>>>(X, W_embed, mask_coarse, b_out, ws, out);
  scan_kernel<<<dim3(512), dim3(256), 0, stream>>>(mask_fine, W_deconv, w1, w2, w_out, ws, out);
}

// Round 11
// 615.191 us; speedup vs baseline: 1.0289x; 1.0289x over previous
//
#include <hip/hip_runtime.h>
#include <math.h>

// ws layout (float offsets)
#define SB_OFF 0           // tagged ring strips [2][256][3584] = 1835008 floats (7.34 MB)
#define E_OFF  1835008     // e [128][2048] = 262144 floats ; total 8.39 MB
#define REC_SZ 3584
#define PAR_SZ 917504      // 256 * REC_SZ
// ring record (floats): HT[8][32]@0  HB[8][32]@512  VL[64][8]@1024  VR[64][8]@2048
//   CTL[8][8]@3072  CTR@3200  CBL@3328  CBR@3456   (all (payload,tag) f2 pairs)

__device__ __forceinline__ float fast_tanh(float x) {
  x = fminf(fmaxf(x, -15.f), 15.f);
  float ex = __expf(2.f * x);
  return __fdividef(ex - 1.f, ex + 1.f);
}

template <int CTRL>
__device__ __forceinline__ float dpp_add(float v) {
  int x = __builtin_amdgcn_update_dpp(0, __float_as_int(v), CTRL, 0xF, 0xF, true);
  return v + __int_as_float(x);
}

__device__ __forceinline__ float2 aload_f2(const float* p) {
  unsigned long long v = __hip_atomic_load((const unsigned long long*)p,
                                           __ATOMIC_RELAXED, __HIP_MEMORY_SCOPE_AGENT);
  float2 r;
  r.x = __uint_as_float((unsigned)v);
  r.y = __uint_as_float((unsigned)(v >> 32));
  return r;
}
__device__ __forceinline__ void astore_f2(float* p, float a, float b) {
  unsigned long long v =
      ((unsigned long long)__float_as_uint(b) << 32) | (unsigned long long)__float_as_uint(a);
  __hip_atomic_store((unsigned long long*)p, v, __ATOMIC_RELAXED, __HIP_MEMORY_SCOPE_AGENT);
}

// ---------------- K0: embed e = (X@W^T)*mask_coarse ; out = bias
__global__ __launch_bounds__(256) void prep_kernel(
    const float* __restrict__ X, const float* __restrict__ W_embed,
    const float* __restrict__ mask_coarse, const float* __restrict__ b_out,
    float* __restrict__ ws, float* __restrict__ out)
{
  const int tid = threadIdx.x, bid = blockIdx.x;  // grid = 512
  float* eb = ws + E_OFF;
  {
    int idx = bid * 256 + tid;                    // 131072 = out_size
    out[idx] = b_out[(idx >> 6) & 15];
  }
  const int o  = bid * 4 + (tid >> 6);            // 2048 rows
  const int t0 = (tid & 63) * 2;                  // 2 t's per thread
  const float4* Wf4 = (const float4*)W_embed + (size_t)o * 128;
  const float4* Xf4 = (const float4*)X;
  float a0 = 0.f, a1 = 0.f;
  for (int k4 = 0; k4 < 128; ++k4) {
    float4 wv = Wf4[k4];                          // wave-uniform -> broadcast
    float4 x0 = Xf4[(size_t)t0 * 128 + k4];
    float4 x1 = Xf4[(size_t)(t0 + 1) * 128 + k4];
    a0 = fmaf(wv.x, x0.x, fmaf(wv.y, x0.y, fmaf(wv.z, x0.z, fmaf(wv.w, x0.w, a0))));
    a1 = fmaf(wv.x, x1.x, fmaf(wv.y, x1.y, fmaf(wv.z, x1.z, fmaf(wv.w, x1.w, a1))));
  }
  float mc = mask_coarse[o & 255];
  eb[(size_t)t0 * 2048 + o]       = a0 * mc;
  eb[(size_t)(t0 + 1) * 2048 + o] = a1 * mc;
}

// ---------------- K1: persistent scan, 2-step temporal blocking.
// 256 blocks x 512 threads; 8 ch x (4x8 tiles of 64x32). State in LDS with
// 8-wide halo; ONE tagged-ring exchange per 2 steps.
__global__ __launch_bounds__(512, 2) void scan_kernel(
    const float* __restrict__ mask_fine, const float* __restrict__ W_deconv,
    const float* __restrict__ w1, const float* __restrict__ w2,
    const float* __restrict__ w_out, float* __restrict__ ws,
    float* __restrict__ out)
{
  __shared__ float zin[80 * 52];     // Z_2p, tile + 8-halo (rows r0-8.., cols c0-8..)
  __shared__ float zmid[72 * 44];    // Z_{2p+1}, extended (rows r0-4.., cols c0-4..)
  __shared__ float rowbuf[64 * 33];  // readout partials: [row][0..15]=y_2p [16..31]=y_2p+1

  const int tid  = threadIdx.x;      // 0..511
  const int bid  = blockIdx.x;
  const int ch   = bid >> 5;
  const int tile = bid & 31;
  const int tI = tile >> 3, tJ = tile & 7;   // 4 x 8
  const int r0 = tI << 6, c0 = tJ << 5;
  const int row = tid >> 3;          // 0..63
  const int cg  = tid & 7;
  const int lc  = cg << 2;

  float* Zb = ws + SB_OFF;
  const float* eb = ws + E_OFF;
  const int myoff = (ch * 32 + tile) * REC_SZ;

  // ---- core (step B) constants
  const int eoffB = ((r0 + row) >> 4) * 16 + ((c0 + lc) >> 4);
  float4 wd[8];
#pragma unroll
  for (int c = 0; c < 8; ++c)
    wd[c] = *(const float4*)&W_deconv[(((c * 8 + ch) * 16) + (row & 15)) * 16 + (lc & 15)];
  float4 mf = *(const float4*)&mask_fine[(size_t)(r0 + row) * 256 + c0 + lc];
  float4 wo[16];
#pragma unroll
  for (int oc = 0; oc < 16; ++oc)
    wo[oc] = *(const float4*)&w_out[(((oc * 8 + ch) * 32) + (row & 31)) * 32 + lc];
  float w1s[9], w2s[25];
#pragma unroll
  for (int k = 0; k < 9; ++k)
    w1s[k] = __uint_as_float(__builtin_amdgcn_readfirstlane(__float_as_uint(w1[ch * 9 + k])));
#pragma unroll
  for (int k = 0; k < 25; ++k)
    w2s[k] = __uint_as_float(__builtin_amdgcn_readfirstlane(__float_as_uint(w2[ch * 25 + k])));

  // ---- step-A group assignments (720 f4 over 512 threads)
  const int nA = (tid < 208) ? 2 : 1;
  int gA_zb[2], gA_zm[2], gA_eoff[2], gA_wdoff[2], gA_mfoff[2];
#pragma unroll
  for (int q = 0; q < 2; ++q) {
    int g = tid + q * 512; if (g >= 720) g = 719;   // dummy for inactive
    int arow = g / 10, acg = g - arow * 10;
    int gr = (r0 - 4 + arow) & 255;
    int gc = (c0 - 4 + 4 * acg) & 255;
    gA_zb[q]    = arow * 52 + 4 * acg;
    gA_zm[q]    = arow * 44 + 4 * acg;
    gA_eoff[q]  = (gr >> 4) * 16 + (gc >> 4);
    gA_wdoff[q] = ch * 256 + (gr & 15) * 16 + (gc & 15);
    gA_mfoff[q] = gr * 256 + gc;
  }

  // ---- halo-read assignments: 1792 tagged words; 3-4 per thread
  const int nR = (tid < 256) ? 4 : 3;
  int rd_off[4], rd_dst[4];
#pragma unroll
  for (int q = 0; q < 4; ++q) {
    int u = tid + q * 512; if (u >= 1792) u = 1791;
    int di = 0, dj = 0, src = 0, dst = 0;
    if (u < 256) {            // top rows 0..7, cols 8..39 <- U.HB
      int r = u >> 5, c = u & 31;
      di = -1; src = 512 + 2 * u; dst = r * 52 + 8 + c;
    } else if (u < 512) {     // bottom rows 72..79 <- D.HT
      int v = u - 256;
      di = 1; src = 2 * v; dst = (72 + (v >> 5)) * 52 + 8 + (v & 31);
    } else if (u < 1024) {    // left rows 8..71, cols 0..7 <- L.VR
      int v = u - 512;
      dj = -1; src = 2048 + 2 * v; dst = (8 + (v >> 3)) * 52 + (v & 7);
    } else if (u < 1536) {    // right rows 8..71, cols 40..47 <- R.VL
      int v = u - 1024;
      dj = 1; src = 1024 + 2 * v; dst = (8 + (v >> 3)) * 52 + 40 + (v & 7);
    } else {                  // corners 4 x 64 words
      int v = u - 1536, corner = v >> 6, k = v & 63, r = k >> 3, c = k & 7;
      if (corner == 0)      { di = -1; dj = -1; src = 3456 + 2 * k; dst = r * 52 + c; }
      else if (corner == 1) { di = -1; dj = 1;  src = 3328 + 2 * k; dst = r * 52 + 40 + c; }
      else if (corner == 2) { di = 1;  dj = -1; src = 3200 + 2 * k; dst = (72 + r) * 52 + c; }
      else                  { di = 1;  dj = 1;  src = 3072 + 2 * k; dst = (72 + r) * 52 + 40 + c; }
    }
    int nI = (tI + di) & 3, nJ = (tJ + dj) & 7;
    rd_off[q] = (ch * 32 + nI * 8 + nJ) * REC_SZ + src;
    rd_dst[q] = dst;
  }

  // init zin = Z_0 = 0 (incl. halo)
  for (int k = tid; k < 80 * 52; k += 512) zin[k] = 0.f;
  __syncthreads();

  // stencil over a 12-wide window from buf (stride S), accumulating c1a/c2a
  auto stencil = [&](const float* buf, int S, int base, float* c1a, float* c2a) {
    float w[12];
    auto load_row = [&](int k) {
      float4 A  = *(const float4*)&buf[base + k * S];
      float4 B  = *(const float4*)&buf[base + k * S + 4];
      float4 Cq = *(const float4*)&buf[base + k * S + 8];
      w[0]=A.x; w[1]=A.y; w[2]=A.z; w[3]=A.w;
      w[4]=B.x; w[5]=B.y; w[6]=B.z; w[7]=B.w;
      w[8]=Cq.x; w[9]=Cq.y; w[10]=Cq.z; w[11]=Cq.w;
    };
    auto k2row = [&](int a) {
#pragma unroll
      for (int j = 0; j < 4; ++j)
#pragma unroll
        for (int b = 0; b < 5; ++b)
          c2a[j] = fmaf(w[j + 2 * b], w2s[a * 5 + b], c2a[j]);
    };
    auto k1row = [&](int a) {
#pragma unroll
      for (int j = 0; j < 4; ++j)
#pragma unroll
        for (int b = 0; b < 3; ++b)
          c1a[j] = fmaf(w[j + 3 + b], w1s[a * 3 + b], c1a[j]);
    };
    load_row(0); k2row(0);
    load_row(2); k2row(1);
    load_row(3); k1row(0);
    load_row(4); k1row(1); k2row(2);
    load_row(5); k1row(2);
    load_row(6); k2row(3);
    load_row(8); k2row(4);
  };

  for (int p = 0; p < 64; ++p) {
    const int t2p = 2 * p;
    float* sb = Zb + (size_t)(p & 1) * PAR_SZ;

    // ======== STEP A: Z_{2p+1} on extended 72x40 region -> zmid
    for (int q = 0; q < nA; ++q) {
      float c1a[4] = {0,0,0,0}, c2a[4] = {0,0,0,0};
      stencil(zin, 52, gA_zb[q], c1a, c2a);
      float evA[8];
#pragma unroll
      for (int c = 0; c < 8; ++c)
        evA[c] = eb[(size_t)t2p * 2048 + c * 256 + gA_eoff[q]];
      float4 mfA = *(const float4*)&mask_fine[gA_mfoff[q]];
      float zr[4];
#pragma unroll
      for (int j = 0; j < 4; ++j) {
        float u = 0.f;
#pragma unroll
        for (int c = 0; c < 8; ++c)
          u = fmaf(evA[c], W_deconv[c * 2048 + gA_wdoff[q] + j], u);
        float val = fmaf(0.9f, c1a[j], fmaf(0.1f, c2a[j], ((const float*)&mfA)[j] * u));
        zr[j] = fast_tanh(val);
      }
      *(float4*)&zmid[gA_zm[q]] = make_float4(zr[0], zr[1], zr[2], zr[3]);
    }
    __syncthreads();  // A1: zmid complete; all zin reads done

    // ======== STEP B: Z_{2p+2} on core from zmid
    float zv[4];
    {
      float c1a[4] = {0,0,0,0}, c2a[4] = {0,0,0,0};
      stencil(zmid, 44, row * 44 + lc, c1a, c2a);
      float evB[8];
#pragma unroll
      for (int c = 0; c < 8; ++c)
        evB[c] = eb[(size_t)(t2p + 1) * 2048 + c * 256 + eoffB];
#pragma unroll
      for (int j = 0; j < 4; ++j) {
        float u = 0.f;
#pragma unroll
        for (int c = 0; c < 8; ++c)
          u = fmaf(evB[c], ((const float*)&wd[c])[j], u);
        float val = fmaf(0.9f, c1a[j], fmaf(0.1f, c2a[j], ((const float*)&mf)[j] * u));
        zv[j] = fast_tanh(val);
      }
    }

    // ---- publish ring of Z_{2p+2} immediately (tag p+1)
    if (p < 63) {
      float* myrec = sb + myoff;
      const float tagf = __uint_as_float((unsigned)(p + 1));
      if (row < 8) {
#pragma unroll
        for (int j = 0; j < 4; ++j) astore_f2(myrec + 2 * (row * 32 + lc + j), zv[j], tagf);
      }
      if (row >= 56) {
#pragma unroll
        for (int j = 0; j < 4; ++j)
          astore_f2(myrec + 512 + 2 * ((row - 56) * 32 + lc + j), zv[j], tagf);
      }
      if (lc < 8) {
#pragma unroll
        for (int j = 0; j < 4; ++j) astore_f2(myrec + 1024 + 2 * (row * 8 + lc + j), zv[j], tagf);
      }
      if (lc >= 24) {
#pragma unroll
        for (int j = 0; j < 4; ++j)
          astore_f2(myrec + 2048 + 2 * (row * 8 + lc - 24 + j), zv[j], tagf);
      }
      if (row < 8 && lc < 8) {
#pragma unroll
        for (int j = 0; j < 4; ++j) astore_f2(myrec + 3072 + 2 * (row * 8 + lc + j), zv[j], tagf);
      }
      if (row < 8 && lc >= 24) {
#pragma unroll
        for (int j = 0; j < 4; ++j)
          astore_f2(myrec + 3200 + 2 * (row * 8 + lc - 24 + j), zv[j], tagf);
      }
      if (row >= 56 && lc < 8) {
#pragma unroll
        for (int j = 0; j < 4; ++j)
          astore_f2(myrec + 3328 + 2 * ((row - 56) * 8 + lc + j), zv[j], tagf);
      }
      if (row >= 56 && lc >= 24) {
#pragma unroll
        for (int j = 0; j < 4; ++j)
          astore_f2(myrec + 3456 + 2 * ((row - 56) * 8 + lc - 24 + j), zv[j], tagf);
      }
    }

    // ---- readouts: y_{2p} from zmid core, y_{2p+1} from zv
    float racc1[16], racc2[16];
    {
      float4 zm = *(const float4*)&zmid[(4 + row) * 44 + 4 + lc];
#pragma unroll
      for (int oc = 0; oc < 16; ++oc) {
        const float* wop = (const float*)&wo[oc];
        racc1[oc] = fmaf(zm.x, wop[0], fmaf(zm.y, wop[1], fmaf(zm.z, wop[2], zm.w * wop[3])));
        racc2[oc] = fmaf(zv[0], wop[0], fmaf(zv[1], wop[1], fmaf(zv[2], wop[2], zv[3] * wop[3])));
      }
    }

    // ---- commit core Z_{2p+2} into zin (halo region written by polls below)
    *(float4*)&zin[(8 + row) * 52 + 8 + lc] = make_float4(zv[0], zv[1], zv[2], zv[3]);

    // ---- octet DPP reduce both readouts -> rowbuf
#pragma unroll
    for (int k = 0; k < 16; ++k) {
      racc1[k] = dpp_add<0xB1>(racc1[k]); racc1[k] = dpp_add<0x4E>(racc1[k]);
      racc1[k] = dpp_add<0x141>(racc1[k]);
      racc2[k] = dpp_add<0xB1>(racc2[k]); racc2[k] = dpp_add<0x4E>(racc2[k]);
      racc2[k] = dpp_add<0x141>(racc2[k]);
    }
    rowbuf[row * 33 + (cg << 1)]          = racc1[cg << 1];
    rowbuf[row * 33 + (cg << 1) + 1]      = racc1[(cg << 1) + 1];
    rowbuf[row * 33 + 16 + (cg << 1)]     = racc2[cg << 1];
    rowbuf[row * 33 + 16 + (cg << 1) + 1] = racc2[(cg << 1) + 1];

    // ---- poll neighbors' rings (tag p+1) -> zin 8-halo
    if (p < 63) {
      const unsigned tg = (unsigned)(p + 1);
      for (int q = 0; q < nR; ++q) {
        const float* pp = sb + rd_off[q];
        float2 v2; int spins = 0;
        do { v2 = aload_f2(pp);
             if (__float_as_uint(v2.y) == tg) break;
             __builtin_amdgcn_s_sleep(1);
        } while (++spins < (1 << 18));   // fail loud (wrong), never hang
        zin[rd_dst[q]] = v2.x;
      }
    }

    __syncthreads();  // B1: zin (core+halo), rowbuf complete

    // ---- stage 2: fold rowbuf -> atomicAdd out (bias pre-initialized)
    if (tid < 64) {
      int half = tid >> 5;               // 0: y_2p, 1: y_2p+1
      int w32  = tid & 31;
      int pidx = w32 >> 4, oc = w32 & 15;
      float s = 0.f;
#pragma unroll
      for (int r = 0; r < 32; ++r) s += rowbuf[(pidx * 32 + r) * 33 + half * 16 + oc];
      atomicAdd(&out[(t2p + half) * 1024 + oc * 64 + (2 * tI + pidx) * 8 + tJ], s);
    }
  }
}

extern "C" void kernel_launch(void* const* d_in, const int* in_sizes, int n_in,
                              void* d_out, int out_size, void* d_ws, size_t ws_size,
                              hipStream_t stream) {
  const float* X           = (const float*)d_in[0];
  const float* W_embed     = (const float*)d_in[1];
  const float* mask_coarse = (const float*)d_in[2];
  const float* mask_fine   = (const float*)d_in[3];
  const float* W_deconv    = (const float*)d_in[4];
  const float* w1          = (const float*)d_in[5];
  const float* w2          = (const float*)d_in[6];
  const float* w_out       = (const float*)d_in[7];
  const float* b_out       = (const float*)d_in[8];
  float* ws  = (float*)d_ws;
  float* out = (float*)d_out;

  prep_kernel<<<dim3(512), dim3(256), 0, stream>>>(X, W_embed, mask_coarse, b_out, ws, out);
  scan_kernel<<<dim3(256), dim3(512), 0, stream>>>(mask_fine, W_deconv, w1, w2, w_out, ws, out);
}

// Round 12
// 573.741 us; speedup vs baseline: 1.1032x; 1.0722x over previous
//
#include <hip/hip_runtime.h>
#include <math.h>

// ws layout (float offsets)
#define SB_OFF   0          // tagged strips [2][8][32][2048] = 1048576 floats
#define E_OFF    1048576    // e [128][2048] = 262144 floats ; total 5.24 MB
// strip record (2048 floats/tile), all entries (payload,tag) f2 pairs:
//   HT[4][32]@0  HB[4][32]@256  VL[64][4]@512  VR[64][4]@1024
//   CTL[4][4]@1536  CTR@1568  CBL@1600  CBR@1632

__device__ __forceinline__ float fast_tanh(float x) {
  x = fminf(fmaxf(x, -15.f), 15.f);
  float ex = __expf(2.f * x);
  return __fdividef(ex - 1.f, ex + 1.f);
}

// octet (8-lane) sum via DPP — pure VALU.
template <int CTRL>
__device__ __forceinline__ float dpp_add(float v) {
  int x = __builtin_amdgcn_update_dpp(0, __float_as_int(v), CTRL, 0xF, 0xF, true);
  return v + __int_as_float(x);
}

// Cross-XCD coherent path: relaxed AGENT-scope atomics at the coherent point.
__device__ __forceinline__ float2 aload_f2(const float* p) {
  unsigned long long v = __hip_atomic_load((const unsigned long long*)p,
                                           __ATOMIC_RELAXED, __HIP_MEMORY_SCOPE_AGENT);
  float2 r;
  r.x = __uint_as_float((unsigned)v);
  r.y = __uint_as_float((unsigned)(v >> 32));
  return r;
}
__device__ __forceinline__ void astore_f2(float* p, float a, float b) {
  unsigned long long v =
      ((unsigned long long)__float_as_uint(b) << 32) | (unsigned long long)__float_as_uint(a);
  __hip_atomic_store((unsigned long long*)p, v, __ATOMIC_RELAXED, __HIP_MEMORY_SCOPE_AGENT);
}

// ---------------- K0: embed e = (X@W^T)*mask_coarse ; out = bias
__global__ __launch_bounds__(256) void prep_kernel(
    const float* __restrict__ X, const float* __restrict__ W_embed,
    const float* __restrict__ mask_coarse, const float* __restrict__ b_out,
    float* __restrict__ ws, float* __restrict__ out)
{
  const int tid = threadIdx.x, bid = blockIdx.x;  // grid = 512
  float* eb = ws + E_OFF;
  {
    int idx = bid * 256 + tid;                    // 131072 = out_size
    out[idx] = b_out[(idx >> 6) & 15];
  }
  const int o  = bid * 4 + (tid >> 6);            // 2048 rows
  const int t0 = (tid & 63) * 2;                  // 2 t's per thread
  const float4* Wf4 = (const float4*)W_embed + (size_t)o * 128;
  const float4* Xf4 = (const float4*)X;
  float a0 = 0.f, a1 = 0.f;
  for (int k4 = 0; k4 < 128; ++k4) {
    float4 wv = Wf4[k4];
    float4 x0 = Xf4[(size_t)t0 * 128 + k4];
    float4 x1 = Xf4[(size_t)(t0 + 1) * 128 + k4];
    a0 = fmaf(wv.x, x0.x, fmaf(wv.y, x0.y, fmaf(wv.z, x0.z, fmaf(wv.w, x0.w, a0))));
    a1 = fmaf(wv.x, x1.x, fmaf(wv.y, x1.y, fmaf(wv.z, x1.z, fmaf(wv.w, x1.w, a1))));
  }
  float mc = mask_coarse[o & 255];
  eb[(size_t)t0 * 2048 + o]       = a0 * mc;
  eb[(size_t)(t0 + 1) * 2048 + o] = a1 * mc;
}

// ---------------- K1: persistent scan. 256 blocks x 512 threads.
// 8 ch x (4x8 tiles of 64x32). Double-buffered LDS state -> ONE barrier/step.
__global__ __launch_bounds__(512, 2) void scan_kernel(
    const float* __restrict__ mask_fine, const float* __restrict__ W_deconv,
    const float* __restrict__ w1, const float* __restrict__ w2,
    const float* __restrict__ w_out, float* __restrict__ ws,
    float* __restrict__ out)
{
  __shared__ float zin[2][72 * 44];     // Z parity buffers, tile + 4-halo (stride 44)
  __shared__ float rowbuf[2][64 * 17];  // readout partials, parity

  const int tid  = threadIdx.x;       // 0..511
  const int bid  = blockIdx.x;
  const int ch   = bid >> 5;
  const int tile = bid & 31;
  const int tI = tile >> 3, tJ = tile & 7;
  const int r0 = tI << 6, c0 = tJ << 5;
  const int row = tid >> 3;           // 0..63
  const int cg  = tid & 7;
  const int lc  = cg << 2;

  float* Zb = ws + SB_OFF;
  const float* eb = ws + E_OFF;
  const int myoff = (ch * 32 + tile) << 11;   // record stride 2048

  // ---- per-thread fixed constants
  const int i0 = (r0 + row) >> 4;
  const int jj = (c0 + lc) >> 4;
  float4 wd[8];
#pragma unroll
  for (int c = 0; c < 8; ++c)
    wd[c] = *(const float4*)&W_deconv[(((c * 8 + ch) * 16) + (row & 15)) * 16 + (lc & 15)];
  float4 mf = *(const float4*)&mask_fine[(size_t)(r0 + row) * 256 + c0 + lc];
  float4 wo[16];
#pragma unroll
  for (int oc = 0; oc < 16; ++oc)
    wo[oc] = *(const float4*)&w_out[(((oc * 8 + ch) * 32) + (row & 31)) * 32 + lc];
  float w1s[9], w2s[25];
#pragma unroll
  for (int k = 0; k < 9; ++k)
    w1s[k] = __uint_as_float(__builtin_amdgcn_readfirstlane(__float_as_uint(w1[ch * 9 + k])));
#pragma unroll
  for (int k = 0; k < 25; ++k)
    w2s[k] = __uint_as_float(__builtin_amdgcn_readfirstlane(__float_as_uint(w2[ch * 25 + k])));

  // ---- fixed halo-read assignments: 832 tagged words; <=2 per thread
  int rd_off[2] = {0, 0}, rd_dst[2] = {0, 0};
  {
    int n = 0;
    auto setup = [&](int u) {
      int di = 0, dj = 0, off = 0, dst = 0;
      if (u < 128) {            // top rows 0..3, cols 4..35  <- U.HB
        int r = u >> 5, c = u & 31;
        di = -1; dj = 0; off = 256 + 2 * u; dst = r * 44 + 4 + c;
      } else if (u < 256) {     // bottom rows 68..71         <- D.HT
        int v = u - 128;
        di = 1; dj = 0; off = 2 * v; dst = (68 + (v >> 5)) * 44 + 4 + (v & 31);
      } else if (u < 512) {     // left rows 4..67, cols 0..3 <- L.VR
        int v = u - 256;
        di = 0; dj = -1; off = 1024 + 2 * v; dst = (4 + (v >> 2)) * 44 + (v & 3);
      } else if (u < 768) {     // right rows 4..67, cols 36..39 <- R.VL
        int v = u - 512;
        di = 0; dj = 1; off = 512 + 2 * v; dst = (4 + (v >> 2)) * 44 + 36 + (v & 3);
      } else {                  // corners, 16 words each
        int v = u - 768; int corner = v >> 4, k = v & 15, r = k >> 2, c = k & 3;
        if (corner == 0)      { di = -1; dj = -1; off = 1632 + 2 * k; dst = r * 44 + c; }
        else if (corner == 1) { di = -1; dj = 1;  off = 1600 + 2 * k; dst = r * 44 + 36 + c; }
        else if (corner == 2) { di = 1;  dj = -1; off = 1568 + 2 * k; dst = (68 + r) * 44 + c; }
        else                  { di = 1;  dj = 1;  off = 1536 + 2 * k; dst = (68 + r) * 44 + 36 + c; }
      }
      int nI = (tI + di) & 3, nJ = (tJ + dj) & 7;
      rd_off[n] = ((ch * 32 + nI * 8 + nJ) << 11) + off;
      rd_dst[n] = dst;
      ++n;
    };
    setup(tid);
    if (tid < 320) setup(tid + 512);
  }
  const bool has2 = (tid < 320);

  // init both parity buffers (Z0 = 0, incl. halo)
  for (int k = tid; k < 2 * 72 * 44; k += 512) zin[0][k] = 0.f;
  __syncthreads();

  for (int t = 0; t < 128; ++t) {
    float* sb = Zb + (size_t)((t + 1) & 1) * 524288;   // tagged strips for Z_{t+1}
    const float* zr = zin[t & 1];
    float*       zw = zin[(t + 1) & 1];
    float*       rb = rowbuf[t & 1];

    // input-path e values (read-only, L2-resident)
    float ev[8];
#pragma unroll
    for (int c = 0; c < 8; ++c)
      ev[c] = eb[(size_t)t * 2048 + c * 256 + i0 * 16 + jj];

    // ---- compute Z_{t+1} for this thread's 4 px (reads zr = Z_t incl halo)
    float c1a[4] = {0, 0, 0, 0}, c2a[4] = {0, 0, 0, 0};
    {
      float w[12];
      auto load_row = [&](int zrr) {
        float4 A  = *(const float4*)&zr[zrr * 44 + lc];
        float4 B  = *(const float4*)&zr[zrr * 44 + lc + 4];
        float4 Cq = *(const float4*)&zr[zrr * 44 + lc + 8];
        w[0]=A.x; w[1]=A.y; w[2]=A.z; w[3]=A.w;
        w[4]=B.x; w[5]=B.y; w[6]=B.z; w[7]=B.w;
        w[8]=Cq.x; w[9]=Cq.y; w[10]=Cq.z; w[11]=Cq.w;
      };
      auto k2row = [&](int a) {
#pragma unroll
        for (int j = 0; j < 4; ++j)
#pragma unroll
          for (int b = 0; b < 5; ++b)
            c2a[j] = fmaf(w[j + 2 * b], w2s[a * 5 + b], c2a[j]);
      };
      auto k1row = [&](int a) {
#pragma unroll
        for (int j = 0; j < 4; ++j)
#pragma unroll
          for (int b = 0; b < 3; ++b)
            c1a[j] = fmaf(w[j + 3 + b], w1s[a * 3 + b], c1a[j]);
      };
      load_row(row + 0); k2row(0);
      load_row(row + 2); k2row(1);
      load_row(row + 3); k1row(0);
      load_row(row + 4); k1row(1); k2row(2);
      load_row(row + 5); k1row(2);
      load_row(row + 6); k2row(3);
      load_row(row + 8); k2row(4);
    }
    float zv[4];
    {
      const float* mfp = (const float*)&mf;
#pragma unroll
      for (int j = 0; j < 4; ++j) {
        float u = 0.f;
#pragma unroll
        for (int c = 0; c < 8; ++c)
          u = fmaf(ev[c], ((const float*)&wd[c])[j], u);
        float val = fmaf(0.9f, c1a[j], fmaf(0.1f, c2a[j], mfp[j] * u));
        zv[j] = fast_tanh(val);
      }
    }

    // ---- publish tagged boundary words immediately (tag t+1)
    if (t < 127) {
      float* myrec = sb + myoff;
      const float tagf = __uint_as_float((unsigned)(t + 1));
      if (row < 4) {
#pragma unroll
        for (int j = 0; j < 4; ++j)
          astore_f2(myrec + 2 * (row * 32 + lc + j), zv[j], tagf);              // HT
      }
      if (row >= 60) {
#pragma unroll
        for (int j = 0; j < 4; ++j)
          astore_f2(myrec + 256 + 2 * ((row - 60) * 32 + lc + j), zv[j], tagf); // HB
      }
      if (lc == 0) {
#pragma unroll
        for (int j = 0; j < 4; ++j)
          astore_f2(myrec + 512 + 2 * (row * 4 + j), zv[j], tagf);              // VL
      }
      if (lc == 28) {
#pragma unroll
        for (int j = 0; j < 4; ++j)
          astore_f2(myrec + 1024 + 2 * (row * 4 + j), zv[j], tagf);             // VR
      }
      if (row < 4 && lc == 0) {
#pragma unroll
        for (int j = 0; j < 4; ++j)
          astore_f2(myrec + 1536 + 2 * (row * 4 + j), zv[j], tagf);             // CTL
      }
      if (row < 4 && lc == 28) {
#pragma unroll
        for (int j = 0; j < 4; ++j)
          astore_f2(myrec + 1568 + 2 * (row * 4 + j), zv[j], tagf);             // CTR
      }
      if (row >= 60 && lc == 0) {
#pragma unroll
        for (int j = 0; j < 4; ++j)
          astore_f2(myrec + 1600 + 2 * ((row - 60) * 4 + j), zv[j], tagf);      // CBL
      }
      if (row >= 60 && lc == 28) {
#pragma unroll
        for (int j = 0; j < 4; ++j)
          astore_f2(myrec + 1632 + 2 * ((row - 60) * 4 + j), zv[j], tagf);      // CBR
      }
    }

    // ---- commit interior into the OTHER parity buffer (no barrier needed)
    *(float4*)&zw[(4 + row) * 44 + 4 + lc] = make_float4(zv[0], zv[1], zv[2], zv[3]);

    // ---- readout FMAs + octet DPP reduce -> rowbuf[parity]
    float racc[16];
#pragma unroll
    for (int oc = 0; oc < 16; ++oc) {
      const float* wop = (const float*)&wo[oc];
      racc[oc] = fmaf(zv[0], wop[0], fmaf(zv[1], wop[1], fmaf(zv[2], wop[2], zv[3] * wop[3])));
    }
#pragma unroll
    for (int k = 0; k < 16; ++k) {
      racc[k] = dpp_add<0xB1>(racc[k]);
      racc[k] = dpp_add<0x4E>(racc[k]);
      racc[k] = dpp_add<0x141>(racc[k]);
    }
    rb[row * 17 + (cg << 1)]     = racc[cg << 1];
    rb[row * 17 + (cg << 1) + 1] = racc[(cg << 1) + 1];

    // ---- halo polls (both loads in flight; re-load only stale) -> zw halo
    if (t < 127) {
      const unsigned tg = (unsigned)(t + 1);
      const float* p0 = sb + rd_off[0];
      const float* p1 = sb + rd_off[has2 ? 1 : 0];
      float2 va = aload_f2(p0);
      float2 vb = aload_f2(p1);
      int spins = 0;
      while ((__float_as_uint(va.y) != tg) || (__float_as_uint(vb.y) != tg)) {
        if (++spins > (1 << 18)) break;   // fail loud (wrong), never hang
        __builtin_amdgcn_s_sleep(1);
        if (__float_as_uint(va.y) != tg) va = aload_f2(p0);
        if (__float_as_uint(vb.y) != tg) vb = aload_f2(p1);
      }
      zw[rd_dst[0]] = va.x;
      if (has2) zw[rd_dst[1]] = vb.x;
    }

    __syncthreads();  // the ONE barrier: zw (interior+halo) + rowbuf complete

    // ---- stage 2: fold rowbuf[parity] -> atomicAdd out (bias pre-initialized)
    if (tid < 32) {
      int p = tid >> 4, oc = tid & 15;
      float s = 0.f;
#pragma unroll
      for (int r = 0; r < 32; ++r) s += rb[(p * 32 + r) * 17 + oc];
      atomicAdd(&out[t * 1024 + oc * 64 + (2 * tI + p) * 8 + tJ], s);
    }
  }
}

extern "C" void kernel_launch(void* const* d_in, const int* in_sizes, int n_in,
                              void* d_out, int out_size, void* d_ws, size_t ws_size,
                              hipStream_t stream) {
  const float* X           = (const float*)d_in[0];
  const float* W_embed     = (const float*)d_in[1];
  const float* mask_coarse = (const float*)d_in[2];
  const float* mask_fine   = (const float*)d_in[3];
  const float* W_deconv    = (const float*)d_in[4];
  const float* w1          = (const float*)d_in[5];
  const float* w2          = (const float*)d_in[6];
  const float* w_out       = (const float*)d_in[7];
  const float* b_out       = (const float*)d_in[8];
  float* ws  = (float*)d_ws;
  float* out = (float*)d_out;

  prep_kernel<<<dim3(512), dim3(256), 0, stream>>>(X, W_embed, mask_coarse, b_out, ws, out);
  scan_kernel<<<dim3(256), dim3(512), 0, stream>>>(mask_fine, W_deconv, w1, w2, w_out, ws, out);
}

// Round 13
// 556.051 us; speedup vs baseline: 1.1383x; 1.0318x over previous
//
#include <hip/hip_runtime.h>
#include <math.h>

// ws layout (float offsets)
#define SB_OFF   0          // strip records [2][256][1024] = 524288 floats (2.1 MB)
#define E_OFF    524288     // e [128][2048] = 262144 floats ; total 3.1 MB
// record (1024 floats): un-tagged f4 payload + per-wave tags
//   HT[4][32]@0  HB[4][32]@128  VL[64][4]@256  VR[64][4]@512
//   CTL[4][4]@768 CTR@784 CBL@800 CBR@816   tags[8] @832 (stride 16 floats)

typedef float vf4 __attribute__((ext_vector_type(4)));

__device__ __forceinline__ float fast_tanh(float x) {
  x = fminf(fmaxf(x, -15.f), 15.f);
  float ex = __expf(2.f * x);
  return __fdividef(ex - 1.f, ex + 1.f);
}

template <int CTRL>
__device__ __forceinline__ float dpp_add(float v) {
  int x = __builtin_amdgcn_update_dpp(0, __float_as_int(v), CTRL, 0xF, 0xF, true);
  return v + __int_as_float(x);
}

// 16B coherent store/load with the same sc0/sc1 flags agent-scope atomics use
// (L1+L2 bypass -> serviced at the coherent point; cross-XCD visible).
__device__ __forceinline__ void st16(float* p, float a, float b, float c, float d) {
  vf4 v; v.x = a; v.y = b; v.z = c; v.w = d;
  asm volatile("global_store_dwordx4 %0, %1, off sc0 sc1" :: "v"(p), "v"(v) : "memory");
}
__device__ __forceinline__ vf4 ld16(const float* p) {
  vf4 r;
  asm volatile("global_load_dwordx4 %0, %1, off sc0 sc1\n"
               "s_waitcnt vmcnt(0)"
               : "=&v"(r) : "v"(p) : "memory");
  return r;
}
// wave-level release: drain this wave's payload stores, THEN publish the tag.
__device__ __forceinline__ void tag_store(unsigned* p, unsigned v) {
  asm volatile("s_waitcnt vmcnt(0)\n"
               "global_store_dword %0, %1, off sc0 sc1" :: "v"(p), "v"(v) : "memory");
}

// ---------------- K0: embed e = (X@W^T)*mask_coarse ; out = bias
__global__ __launch_bounds__(256) void prep_kernel(
    const float* __restrict__ X, const float* __restrict__ W_embed,
    const float* __restrict__ mask_coarse, const float* __restrict__ b_out,
    float* __restrict__ ws, float* __restrict__ out)
{
  const int tid = threadIdx.x, bid = blockIdx.x;  // grid = 512
  float* eb = ws + E_OFF;
  {
    int idx = bid * 256 + tid;                    // 131072 = out_size
    out[idx] = b_out[(idx >> 6) & 15];
  }
  const int o  = bid * 4 + (tid >> 6);            // 2048 rows
  const int t0 = (tid & 63) * 2;                  // 2 t's per thread
  const float4* Wf4 = (const float4*)W_embed + (size_t)o * 128;
  const float4* Xf4 = (const float4*)X;
  float a0 = 0.f, a1 = 0.f;
  for (int k4 = 0; k4 < 128; ++k4) {
    float4 wv = Wf4[k4];
    float4 x0 = Xf4[(size_t)t0 * 128 + k4];
    float4 x1 = Xf4[(size_t)(t0 + 1) * 128 + k4];
    a0 = fmaf(wv.x, x0.x, fmaf(wv.y, x0.y, fmaf(wv.z, x0.z, fmaf(wv.w, x0.w, a0))));
    a1 = fmaf(wv.x, x1.x, fmaf(wv.y, x1.y, fmaf(wv.z, x1.z, fmaf(wv.w, x1.w, a1))));
  }
  float mc = mask_coarse[o & 255];
  eb[(size_t)t0 * 2048 + o]       = a0 * mc;
  eb[(size_t)(t0 + 1) * 2048 + o] = a1 * mc;
}

// ---------------- K1: persistent scan. 256 blocks x 512 threads.
// 8 ch x (4x8 tiles of 64x32). Double-buffered LDS state, ONE barrier/step.
// Exchange: packed 16B sc0sc1 payload + per-wave release tags.
__global__ __launch_bounds__(512, 2) void scan_kernel(
    const float* __restrict__ mask_fine, const float* __restrict__ W_deconv,
    const float* __restrict__ w1, const float* __restrict__ w2,
    const float* __restrict__ w_out, float* __restrict__ ws,
    float* __restrict__ out)
{
  __shared__ float zin[2][72 * 44];     // Z parity buffers, tile + 4-halo
  __shared__ float rowbuf[2][64 * 17];  // readout partials, parity

  const int tid  = threadIdx.x;       // 0..511
  const int bid  = blockIdx.x;
  const int ch   = bid >> 5;
  const int tile = bid & 31;
  const int tI = tile >> 3, tJ = tile & 7;
  const int r0 = tI << 6, c0 = tJ << 5;
  const int row = tid >> 3;           // 0..63
  const int cg  = tid & 7;
  const int lc  = cg << 2;

  float* Zb = ws + SB_OFF;
  const float* eb = ws + E_OFF;
  const int myoff = (ch * 32 + tile) << 10;   // record stride 1024

  // ---- per-thread fixed constants
  const int i0 = (r0 + row) >> 4;
  const int jj = (c0 + lc) >> 4;
  float4 wd[8];
#pragma unroll
  for (int c = 0; c < 8; ++c)
    wd[c] = *(const float4*)&W_deconv[(((c * 8 + ch) * 16) + (row & 15)) * 16 + (lc & 15)];
  float4 mf = *(const float4*)&mask_fine[(size_t)(r0 + row) * 256 + c0 + lc];
  float4 wo[16];
#pragma unroll
  for (int oc = 0; oc < 16; ++oc)
    wo[oc] = *(const float4*)&w_out[(((oc * 8 + ch) * 32) + (row & 31)) * 32 + lc];
  float w1s[9], w2s[25];
#pragma unroll
  for (int k = 0; k < 9; ++k)
    w1s[k] = __uint_as_float(__builtin_amdgcn_readfirstlane(__float_as_uint(w1[ch * 9 + k])));
#pragma unroll
  for (int k = 0; k < 25; ++k)
    w2s[k] = __uint_as_float(__builtin_amdgcn_readfirstlane(__float_as_uint(w2[ch * 25 + k])));

  // ---- fixed halo-read assignment: 208 f4 chunks; 1 per thread (tid<208)
  int rd_src = 0, rd_dst = 0, rd_tag = 0;
  const bool hasrd = (tid < 208);
  if (hasrd) {
    int u = tid, di = 0, dj = 0, src = 0, dst = 0, wv = 0;
    if (u < 32) {              // top rows 0..3 <- U.HB (U wave 7)
      di = -1; src = 128 + (u >> 3) * 32 + (u & 7) * 4;
      dst = (u >> 3) * 44 + 4 + (u & 7) * 4; wv = 7;
    } else if (u < 64) {       // bottom rows 68..71 <- D.HT (D wave 0)
      int v = u - 32; di = 1; src = (v >> 3) * 32 + (v & 7) * 4;
      dst = (68 + (v >> 3)) * 44 + 4 + (v & 7) * 4; wv = 0;
    } else if (u < 128) {      // left rows 4..67 <- L.VR (L wave v/8)
      int v = u - 64; dj = -1; src = 512 + v * 4; dst = (4 + v) * 44; wv = v >> 3;
    } else if (u < 192) {      // right rows 4..67 <- R.VL (R wave v/8)
      int v = u - 128; dj = 1; src = 256 + v * 4; dst = (4 + v) * 44 + 36; wv = v >> 3;
    } else {                   // corners, 4 chunks each
      int v = u - 192, c = v >> 2, r = v & 3;
      if (c == 0)      { di = -1; dj = -1; src = 816 + r * 4; dst = r * 44;            wv = 7; }
      else if (c == 1) { di = -1; dj = 1;  src = 800 + r * 4; dst = r * 44 + 36;       wv = 7; }
      else if (c == 2) { di = 1;  dj = -1; src = 784 + r * 4; dst = (68 + r) * 44;     wv = 0; }
      else             { di = 1;  dj = 1;  src = 768 + r * 4; dst = (68 + r) * 44 + 36; wv = 0; }
    }
    int nI = (tI + di) & 3, nJ = (tJ + dj) & 7;
    int roff = (ch * 32 + nI * 8 + nJ) << 10;
    rd_src = roff + src;
    rd_tag = roff + 832 + wv * 16;
    rd_dst = dst;
  }

  // init both parity buffers (Z0 = 0, incl. halo)
  for (int k = tid; k < 2 * 72 * 44; k += 512) zin[0][k] = 0.f;
  __syncthreads();

  for (int t = 0; t < 128; ++t) {
    float* sb = Zb + (size_t)((t + 1) & 1) * 262144;   // records for Z_{t+1}
    const float* zr = zin[t & 1];
    float*       zw = zin[(t + 1) & 1];
    float*       rb = rowbuf[t & 1];

    // input-path e values (read-only, L2-resident)
    float ev[8];
#pragma unroll
    for (int c = 0; c < 8; ++c)
      ev[c] = eb[(size_t)t * 2048 + c * 256 + i0 * 16 + jj];

    // ---- compute Z_{t+1} for this thread's 4 px (reads zr = Z_t incl halo)
    float c1a[4] = {0, 0, 0, 0}, c2a[4] = {0, 0, 0, 0};
    {
      float w[12];
      auto load_row = [&](int zrr) {
        float4 A  = *(const float4*)&zr[zrr * 44 + lc];
        float4 B  = *(const float4*)&zr[zrr * 44 + lc + 4];
        float4 Cq = *(const float4*)&zr[zrr * 44 + lc + 8];
        w[0]=A.x; w[1]=A.y; w[2]=A.z; w[3]=A.w;
        w[4]=B.x; w[5]=B.y; w[6]=B.z; w[7]=B.w;
        w[8]=Cq.x; w[9]=Cq.y; w[10]=Cq.z; w[11]=Cq.w;
      };
      auto k2row = [&](int a) {
#pragma unroll
        for (int j = 0; j < 4; ++j)
#pragma unroll
          for (int b = 0; b < 5; ++b)
            c2a[j] = fmaf(w[j + 2 * b], w2s[a * 5 + b], c2a[j]);
      };
      auto k1row = [&](int a) {
#pragma unroll
        for (int j = 0; j < 4; ++j)
#pragma unroll
          for (int b = 0; b < 3; ++b)
            c1a[j] = fmaf(w[j + 3 + b], w1s[a * 3 + b], c1a[j]);
      };
      load_row(row + 0); k2row(0);
      load_row(row + 2); k2row(1);
      load_row(row + 3); k1row(0);
      load_row(row + 4); k1row(1); k2row(2);
      load_row(row + 5); k1row(2);
      load_row(row + 6); k2row(3);
      load_row(row + 8); k2row(4);
    }
    float zv[4];
    {
      const float* mfp = (const float*)&mf;
#pragma unroll
      for (int j = 0; j < 4; ++j) {
        float u = 0.f;
#pragma unroll
        for (int c = 0; c < 8; ++c)
          u = fmaf(ev[c], ((const float*)&wd[c])[j], u);
        float val = fmaf(0.9f, c1a[j], fmaf(0.1f, c2a[j], mfp[j] * u));
        zv[j] = fast_tanh(val);
      }
    }

    // ---- publish packed 16B boundary chunks, then per-wave release tag
    if (t < 127) {
      float* rec = sb + myoff;
      if (row < 4)   st16(rec + row * 32 + lc, zv[0], zv[1], zv[2], zv[3]);            // HT
      if (row >= 60) st16(rec + 128 + (row - 60) * 32 + lc, zv[0], zv[1], zv[2], zv[3]); // HB
      if (lc == 0)   st16(rec + 256 + row * 4, zv[0], zv[1], zv[2], zv[3]);            // VL
      if (lc == 28)  st16(rec + 512 + row * 4, zv[0], zv[1], zv[2], zv[3]);            // VR
      if (row < 4 && lc == 0)   st16(rec + 768 + row * 4, zv[0], zv[1], zv[2], zv[3]); // CTL
      if (row < 4 && lc == 28)  st16(rec + 784 + row * 4, zv[0], zv[1], zv[2], zv[3]); // CTR
      if (row >= 60 && lc == 0) st16(rec + 800 + (row - 60) * 4, zv[0], zv[1], zv[2], zv[3]); // CBL
      if (row >= 60 && lc == 28) st16(rec + 816 + (row - 60) * 4, zv[0], zv[1], zv[2], zv[3]); // CBR
      if ((tid & 63) == 0)
        tag_store((unsigned*)(rec + 832 + (tid >> 6) * 16), (unsigned)(t + 1));
    }

    // ---- commit interior into the OTHER parity buffer
    *(float4*)&zw[(4 + row) * 44 + 4 + lc] = make_float4(zv[0], zv[1], zv[2], zv[3]);

    // ---- readout FMAs + octet DPP reduce -> rowbuf[parity]
    float racc[16];
#pragma unroll
    for (int oc = 0; oc < 16; ++oc) {
      const float* wop = (const float*)&wo[oc];
      racc[oc] = fmaf(zv[0], wop[0], fmaf(zv[1], wop[1], fmaf(zv[2], wop[2], zv[3] * wop[3])));
    }
#pragma unroll
    for (int k = 0; k < 16; ++k) {
      racc[k] = dpp_add<0xB1>(racc[k]);
      racc[k] = dpp_add<0x4E>(racc[k]);
      racc[k] = dpp_add<0x141>(racc[k]);
    }
    rb[row * 17 + (cg << 1)]     = racc[cg << 1];
    rb[row * 17 + (cg << 1) + 1] = racc[(cg << 1) + 1];

    // ---- halo: poll producer-wave tag (acquire), then 16B payload load
    if (t < 127 && hasrd) {
      const unsigned tg = (unsigned)(t + 1);
      const unsigned* ta = (const unsigned*)(sb + rd_tag);
      int spins = 0;
      while (__hip_atomic_load(ta, __ATOMIC_RELAXED, __HIP_MEMORY_SCOPE_AGENT) != tg) {
        __builtin_amdgcn_s_sleep(1);
        if (++spins > (1 << 18)) break;  // fail loud (wrong), never hang
      }
      vf4 v = ld16(sb + rd_src);
      zw[rd_dst]     = v.x;
      zw[rd_dst + 1] = v.y;
      zw[rd_dst + 2] = v.z;
      zw[rd_dst + 3] = v.w;
    }

    __syncthreads();  // the ONE barrier: zw (interior+halo) + rowbuf complete

    // ---- stage 2: fold rowbuf[parity] -> atomicAdd out (bias pre-initialized)
    if (tid < 32) {
      int p = tid >> 4, oc = tid & 15;
      float s = 0.f;
#pragma unroll
      for (int r = 0; r < 32; ++r) s += rb[(p * 32 + r) * 17 + oc];
      atomicAdd(&out[t * 1024 + oc * 64 + (2 * tI + p) * 8 + tJ], s);
    }
  }
}

extern "C" void kernel_launch(void* const* d_in, const int* in_sizes, int n_in,
                              void* d_out, int out_size, void* d_ws, size_t ws_size,
                              hipStream_t stream) {
  const float* X           = (const float*)d_in[0];
  const float* W_embed     = (const float*)d_in[1];
  const float* mask_coarse = (const float*)d_in[2];
  const float* mask_fine   = (const float*)d_in[3];
  const float* W_deconv    = (const float*)d_in[4];
  const float* w1          = (const float*)d_in[5];
  const float* w2          = (const float*)d_in[6];
  const float* w_out       = (const float*)d_in[7];
  const float* b_out       = (const float*)d_in[8];
  float* ws  = (float*)d_ws;
  float* out = (float*)d_out;

  prep_kernel<<<dim3(512), dim3(256), 0, stream>>>(X, W_embed, mask_coarse, b_out, ws, out);
  scan_kernel<<<dim3(256), dim3(512), 0, stream>>>(mask_fine, W_deconv, w1, w2, w_out, ws, out);
}

// Round 14
// 517.506 us; speedup vs baseline: 1.2231x; 1.0745x over previous
//
#include <hip/hip_runtime.h>
#include <math.h>

// ws layout (float offsets)
#define SB_OFF   0          // strip records [2][256][1024] = 524288 floats (2.1 MB)
#define E_OFF    524288     // e [128][2048] = 262144 floats ; total 3.1 MB
// record (1024 floats): un-tagged f4 payload + per-wave tags
//   HT[4][32]@0  HB[4][32]@128  VL[64][4]@256  VR[64][4]@512
//   CTL[4][4]@768 CTR@784 CBL@800 CBR@816   tags[8] @832 (stride 16 floats)

typedef float vf4 __attribute__((ext_vector_type(4)));

__device__ __forceinline__ float fast_tanh(float x) {
  x = fminf(fmaxf(x, -15.f), 15.f);
  float ex = __expf(2.f * x);
  return __fdividef(ex - 1.f, ex + 1.f);
}

template <int CTRL>
__device__ __forceinline__ float dpp_add(float v) {
  int x = __builtin_amdgcn_update_dpp(0, __float_as_int(v), CTRL, 0xF, 0xF, true);
  return v + __int_as_float(x);
}

// 16B coherent store/load with the same sc0/sc1 flags agent-scope atomics use
// (L1+L2 bypass -> serviced at the coherent point; cross-XCD visible).
__device__ __forceinline__ void st16(float* p, float a, float b, float c, float d) {
  vf4 v; v.x = a; v.y = b; v.z = c; v.w = d;
  asm volatile("global_store_dwordx4 %0, %1, off sc0 sc1" :: "v"(p), "v"(v) : "memory");
}
__device__ __forceinline__ vf4 ld16(const float* p) {
  vf4 r;
  asm volatile("global_load_dwordx4 %0, %1, off sc0 sc1\n"
               "s_waitcnt vmcnt(0)"
               : "=&v"(r) : "v"(p) : "memory");
  return r;
}
// wave-level release: drain this wave's payload stores, THEN publish the tag.
__device__ __forceinline__ void tag_store(unsigned* p, unsigned v) {
  asm volatile("s_waitcnt vmcnt(0)\n"
               "global_store_dword %0, %1, off sc0 sc1" :: "v"(p), "v"(v) : "memory");
}

// ---------------- K0: embed e = (X@W^T)*mask_coarse ; out = bias
// 256 blocks x 256 thr; block = 8 o-rows x 128 t, k-chunked LDS tiling.
// X staged COALESCED (fixes the 2KB-strided lane reads of the old prep).
__global__ __launch_bounds__(256) void prep_kernel(
    const float* __restrict__ X, const float* __restrict__ W_embed,
    const float* __restrict__ mask_coarse, const float* __restrict__ b_out,
    float* __restrict__ ws, float* __restrict__ out)
{
  __shared__ float Xl[128][36];   // 128 t x 32 k chunk (pad 36 -> conflict-light)
  __shared__ float Wl[8][36];     // 8 o x 32 k chunk

  const int tid = threadIdx.x, bid = blockIdx.x;  // grid = 256
  float* eb = ws + E_OFF;

  // out = bias (scan_kernel atomicAdds channel contributions on top)
  {
    int idx = bid * 512 + tid * 2;                // 131072 = out_size
    out[idx]     = b_out[(idx >> 6) & 15];
    out[idx + 1] = b_out[((idx + 1) >> 6) & 15];
  }

  const int o0 = bid * 8;
  const int ol = tid & 7;          // o-local 0..7
  const int tg = tid >> 3;         // t-group 0..31 (4 t each)
  float acc[4] = {0.f, 0.f, 0.f, 0.f};

  for (int k0 = 0; k0 < 512; k0 += 32) {
    __syncthreads();  // protect Xl/Wl against reuse from previous chunk
    // stage X[128][32]: 16 floats/thread, lanes read consecutive k -> coalesced
#pragma unroll
    for (int p = 0; p < 4; ++p) {
      int tr = p * 32 + (tid >> 3);
      int kc = (tid & 7) * 4;
      *(float4*)&Xl[tr][kc] = *(const float4*)&X[(size_t)tr * 512 + k0 + kc];
    }
    if (tid < 64) {
      int wr = tid >> 3, wc = (tid & 7) * 4;
      *(float4*)&Wl[wr][wc] = *(const float4*)&W_embed[(size_t)(o0 + wr) * 512 + k0 + wc];
    }
    __syncthreads();
#pragma unroll
    for (int kk = 0; kk < 8; ++kk) {
      float4 w4 = *(const float4*)&Wl[ol][kk * 4];
#pragma unroll
      for (int i = 0; i < 4; ++i) {
        float4 x4 = *(const float4*)&Xl[tg * 4 + i][kk * 4];
        acc[i] = fmaf(w4.x, x4.x, fmaf(w4.y, x4.y, fmaf(w4.z, x4.z, fmaf(w4.w, x4.w, acc[i]))));
      }
    }
  }
  const int o = o0 + ol;
  float mc = mask_coarse[o & 255];
#pragma unroll
  for (int i = 0; i < 4; ++i)
    eb[(size_t)(tg * 4 + i) * 2048 + o] = acc[i] * mc;
}

// ---------------- K1: persistent scan. 256 blocks x 512 threads.
// 8 ch x (4x8 tiles of 64x32). Double-buffered LDS state, ONE barrier/step.
// Exchange: packed 16B sc0sc1 payload + per-wave release tags. (r13-verified)
__global__ __launch_bounds__(512, 2) void scan_kernel(
    const float* __restrict__ mask_fine, const float* __restrict__ W_deconv,
    const float* __restrict__ w1, const float* __restrict__ w2,
    const float* __restrict__ w_out, float* __restrict__ ws,
    float* __restrict__ out)
{
  __shared__ float zin[2][72 * 44];     // Z parity buffers, tile + 4-halo
  __shared__ float rowbuf[2][64 * 17];  // readout partials, parity

  const int tid  = threadIdx.x;       // 0..511
  const int bid  = blockIdx.x;
  const int ch   = bid >> 5;
  const int tile = bid & 31;
  const int tI = tile >> 3, tJ = tile & 7;
  const int r0 = tI << 6, c0 = tJ << 5;
  const int row = tid >> 3;           // 0..63
  const int cg  = tid & 7;
  const int lc  = cg << 2;

  float* Zb = ws + SB_OFF;
  const float* eb = ws + E_OFF;
  const int myoff = (ch * 32 + tile) << 10;   // record stride 1024

  // ---- per-thread fixed constants
  const int i0 = (r0 + row) >> 4;
  const int jj = (c0 + lc) >> 4;
  float4 wd[8];
#pragma unroll
  for (int c = 0; c < 8; ++c)
    wd[c] = *(const float4*)&W_deconv[(((c * 8 + ch) * 16) + (row & 15)) * 16 + (lc & 15)];
  float4 mf = *(const float4*)&mask_fine[(size_t)(r0 + row) * 256 + c0 + lc];
  float4 wo[16];
#pragma unroll
  for (int oc = 0; oc < 16; ++oc)
    wo[oc] = *(const float4*)&w_out[(((oc * 8 + ch) * 32) + (row & 31)) * 32 + lc];
  // fold S1=0.9 / S2=0.1 into the lateral weights (saves 2 FMA per j per px)
  float w1s[9], w2s[25];
#pragma unroll
  for (int k = 0; k < 9; ++k)
    w1s[k] = 0.9f * __uint_as_float(__builtin_amdgcn_readfirstlane(__float_as_uint(w1[ch * 9 + k])));
#pragma unroll
  for (int k = 0; k < 25; ++k)
    w2s[k] = 0.1f * __uint_as_float(__builtin_amdgcn_readfirstlane(__float_as_uint(w2[ch * 25 + k])));

  // ---- fixed halo-read assignment: 208 f4 chunks; 1 per thread (tid<208)
  int rd_src = 0, rd_dst = 0, rd_tag = 0;
  const bool hasrd = (tid < 208);
  if (hasrd) {
    int u = tid, di = 0, dj = 0, src = 0, dst = 0, wv = 0;
    if (u < 32) {              // top rows 0..3 <- U.HB (U wave 7)
      di = -1; src = 128 + (u >> 3) * 32 + (u & 7) * 4;
      dst = (u >> 3) * 44 + 4 + (u & 7) * 4; wv = 7;
    } else if (u < 64) {       // bottom rows 68..71 <- D.HT (D wave 0)
      int v = u - 32; di = 1; src = (v >> 3) * 32 + (v & 7) * 4;
      dst = (68 + (v >> 3)) * 44 + 4 + (v & 7) * 4; wv = 0;
    } else if (u < 128) {      // left rows 4..67 <- L.VR (L wave v/8)
      int v = u - 64; dj = -1; src = 512 + v * 4; dst = (4 + v) * 44; wv = v >> 3;
    } else if (u < 192) {      // right rows 4..67 <- R.VL (R wave v/8)
      int v = u - 128; dj = 1; src = 256 + v * 4; dst = (4 + v) * 44 + 36; wv = v >> 3;
    } else {                   // corners, 4 chunks each
      int v = u - 192, c = v >> 2, r = v & 3;
      if (c == 0)      { di = -1; dj = -1; src = 816 + r * 4; dst = r * 44;            wv = 7; }
      else if (c == 1) { di = -1; dj = 1;  src = 800 + r * 4; dst = r * 44 + 36;       wv = 7; }
      else if (c == 2) { di = 1;  dj = -1; src = 784 + r * 4; dst = (68 + r) * 44;     wv = 0; }
      else             { di = 1;  dj = 1;  src = 768 + r * 4; dst = (68 + r) * 44 + 36; wv = 0; }
    }
    int nI = (tI + di) & 3, nJ = (tJ + dj) & 7;
    int roff = (ch * 32 + nI * 8 + nJ) << 10;
    rd_src = roff + src;
    rd_tag = roff + 832 + wv * 16;
    rd_dst = dst;
  }

  // init both parity buffers (Z0 = 0, incl. halo)
  for (int k = tid; k < 2 * 72 * 44; k += 512) zin[0][k] = 0.f;
  __syncthreads();

  for (int t = 0; t < 128; ++t) {
    float* sb = Zb + (size_t)((t + 1) & 1) * 262144;   // records for Z_{t+1}
    const float* zr = zin[t & 1];
    float*       zw = zin[(t + 1) & 1];
    float*       rb = rowbuf[t & 1];

    // input-path e values (read-only, L2-resident)
    float ev[8];
#pragma unroll
    for (int c = 0; c < 8; ++c)
      ev[c] = eb[(size_t)t * 2048 + c * 256 + i0 * 16 + jj];

    // ---- compute Z_{t+1} for this thread's 4 px (reads zr = Z_t incl halo)
    float c1a[4] = {0, 0, 0, 0}, c2a[4] = {0, 0, 0, 0};
    {
      float w[12];
      auto load_row = [&](int zrr) {
        float4 A  = *(const float4*)&zr[zrr * 44 + lc];
        float4 B  = *(const float4*)&zr[zrr * 44 + lc + 4];
        float4 Cq = *(const float4*)&zr[zrr * 44 + lc + 8];
        w[0]=A.x; w[1]=A.y; w[2]=A.z; w[3]=A.w;
        w[4]=B.x; w[5]=B.y; w[6]=B.z; w[7]=B.w;
        w[8]=Cq.x; w[9]=Cq.y; w[10]=Cq.z; w[11]=Cq.w;
      };
      auto k2row = [&](int a) {
#pragma unroll
        for (int j = 0; j < 4; ++j)
#pragma unroll
          for (int b = 0; b < 5; ++b)
            c2a[j] = fmaf(w[j + 2 * b], w2s[a * 5 + b], c2a[j]);
      };
      auto k1row = [&](int a) {
#pragma unroll
        for (int j = 0; j < 4; ++j)
#pragma unroll
          for (int b = 0; b < 3; ++b)
            c1a[j] = fmaf(w[j + 3 + b], w1s[a * 3 + b], c1a[j]);
      };
      load_row(row + 0); k2row(0);
      load_row(row + 2); k2row(1);
      load_row(row + 3); k1row(0);
      load_row(row + 4); k1row(1); k2row(2);
      load_row(row + 5); k1row(2);
      load_row(row + 6); k2row(3);
      load_row(row + 8); k2row(4);
    }
    float zv[4];
    {
      const float* mfp = (const float*)&mf;
#pragma unroll
      for (int j = 0; j < 4; ++j) {
        float u = 0.f;
#pragma unroll
        for (int c = 0; c < 8; ++c)
          u = fmaf(ev[c], ((const float*)&wd[c])[j], u);
        // scales folded into w1s/w2s: val = c1a + c2a + mf*u
        float val = c1a[j] + fmaf(mfp[j], u, c2a[j]);
        zv[j] = fast_tanh(val);
      }
    }

    // ---- publish packed 16B boundary chunks, then per-wave release tag
    if (t < 127) {
      float* rec = sb + myoff;
      if (row < 4)   st16(rec + row * 32 + lc, zv[0], zv[1], zv[2], zv[3]);            // HT
      if (row >= 60) st16(rec + 128 + (row - 60) * 32 + lc, zv[0], zv[1], zv[2], zv[3]); // HB
      if (lc == 0)   st16(rec + 256 + row * 4, zv[0], zv[1], zv[2], zv[3]);            // VL
      if (lc == 28)  st16(rec + 512 + row * 4, zv[0], zv[1], zv[2], zv[3]);            // VR
      if (row < 4 && lc == 0)   st16(rec + 768 + row * 4, zv[0], zv[1], zv[2], zv[3]); // CTL
      if (row < 4 && lc == 28)  st16(rec + 784 + row * 4, zv[0], zv[1], zv[2], zv[3]); // CTR
      if (row >= 60 && lc == 0) st16(rec + 800 + (row - 60) * 4, zv[0], zv[1], zv[2], zv[3]); // CBL
      if (row >= 60 && lc == 28) st16(rec + 816 + (row - 60) * 4, zv[0], zv[1], zv[2], zv[3]); // CBR
      if ((tid & 63) == 0)
        tag_store((unsigned*)(rec + 832 + (tid >> 6) * 16), (unsigned)(t + 1));
    }

    // ---- commit interior into the OTHER parity buffer
    *(float4*)&zw[(4 + row) * 44 + 4 + lc] = make_float4(zv[0], zv[1], zv[2], zv[3]);

    // ---- readout FMAs + octet DPP reduce -> rowbuf[parity]
    float racc[16];
#pragma unroll
    for (int oc = 0; oc < 16; ++oc) {
      const float* wop = (const float*)&wo[oc];
      racc[oc] = fmaf(zv[0], wop[0], fmaf(zv[1], wop[1], fmaf(zv[2], wop[2], zv[3] * wop[3])));
    }
#pragma unroll
    for (int k = 0; k < 16; ++k) {
      racc[k] = dpp_add<0xB1>(racc[k]);
      racc[k] = dpp_add<0x4E>(racc[k]);
      racc[k] = dpp_add<0x141>(racc[k]);
    }
    rb[row * 17 + (cg << 1)]     = racc[cg << 1];
    rb[row * 17 + (cg << 1) + 1] = racc[(cg << 1) + 1];

    // ---- halo: poll producer-wave tag (acquire), then 16B payload load
    if (t < 127 && hasrd) {
      const unsigned tg = (unsigned)(t + 1);
      const unsigned* ta = (const unsigned*)(sb + rd_tag);
      int spins = 0;
      while (__hip_atomic_load(ta, __ATOMIC_RELAXED, __HIP_MEMORY_SCOPE_AGENT) != tg) {
        __builtin_amdgcn_s_sleep(1);
        if (++spins > (1 << 18)) break;  // fail loud (wrong), never hang
      }
      vf4 v = ld16(sb + rd_src);
      zw[rd_dst]     = v.x;
      zw[rd_dst + 1] = v.y;
      zw[rd_dst + 2] = v.z;
      zw[rd_dst + 3] = v.w;
    }

    __syncthreads();  // the ONE barrier: zw (interior+halo) + rowbuf complete

    // ---- stage 2: fold rowbuf[parity] -> atomicAdd out (bias pre-initialized)
    if (tid < 32) {
      int p = tid >> 4, oc = tid & 15;
      float s = 0.f;
#pragma unroll
      for (int r = 0; r < 32; ++r) s += rb[(p * 32 + r) * 17 + oc];
      atomicAdd(&out[t * 1024 + oc * 64 + (2 * tI + p) * 8 + tJ], s);
    }
  }
}

extern "C" void kernel_launch(void* const* d_in, const int* in_sizes, int n_in,
                              void* d_out, int out_size, void* d_ws, size_t ws_size,
                              hipStream_t stream) {
  const float* X           = (const float*)d_in[0];
  const float* W_embed     = (const float*)d_in[1];
  const float* mask_coarse = (const float*)d_in[2];
  const float* mask_fine   = (const float*)d_in[3];
  const float* W_deconv    = (const float*)d_in[4];
  const float* w1          = (const float*)d_in[5];
  const float* w2          = (const float*)d_in[6];
  const float* w_out       = (const float*)d_in[7];
  const float* b_out       = (const float*)d_in[8];
  float* ws  = (float*)d_ws;
  float* out = (float*)d_out;

  prep_kernel<<<dim3(256), dim3(256), 0, stream>>>(X, W_embed, mask_coarse, b_out, ws, out);
  scan_kernel<<<dim3(256), dim3(512), 0, stream>>>(mask_fine, W_deconv, w1, w2, w_out, ws, out);
}

// Round 15
// 507.968 us; speedup vs baseline: 1.2461x; 1.0188x over previous
//
#include <hip/hip_runtime.h>
#include <math.h>

// ws layout (float offsets)
#define SB_OFF   0          // strip records [2][256][1024] = 524288 floats (2.1 MB)
#define E_OFF    524288     // e [128][2048] = 262144 floats ; total 3.1 MB
// record (1024 floats): un-tagged f4 payload + per-wave tags
//   HT[4][32]@0  HB[4][32]@128  VL[64][4]@256  VR[64][4]@512
//   CTL[4][4]@768 CTR@784 CBL@800 CBR@816   tags[8] @832 (stride 16 floats)

typedef float vf4 __attribute__((ext_vector_type(4)));

__device__ __forceinline__ float fast_tanh(float x) {
  x = fminf(fmaxf(x, -15.f), 15.f);
  float ex = __expf(2.f * x);
  return __fdividef(ex - 1.f, ex + 1.f);
}

template <int CTRL>
__device__ __forceinline__ float dpp_add(float v) {
  int x = __builtin_amdgcn_update_dpp(0, __float_as_int(v), CTRL, 0xF, 0xF, true);
  return v + __int_as_float(x);
}

// 16B coherent store/load with the same sc0/sc1 flags agent-scope atomics use
// (L1+L2 bypass -> serviced at the coherent point; cross-XCD visible).
__device__ __forceinline__ void st16(float* p, float a, float b, float c, float d) {
  vf4 v; v.x = a; v.y = b; v.z = c; v.w = d;
  asm volatile("global_store_dwordx4 %0, %1, off sc0 sc1" :: "v"(p), "v"(v) : "memory");
}
__device__ __forceinline__ vf4 ld16(const float* p) {
  vf4 r;
  asm volatile("global_load_dwordx4 %0, %1, off sc0 sc1\n"
               "s_waitcnt vmcnt(0)"
               : "=&v"(r) : "v"(p) : "memory");
  return r;
}
// wave-level release: drain this wave's payload stores, THEN publish the tag.
__device__ __forceinline__ void tag_store(unsigned* p, unsigned v) {
  asm volatile("s_waitcnt vmcnt(0)\n"
               "global_store_dword %0, %1, off sc0 sc1" :: "v"(p), "v"(v) : "memory");
}

// ---------------- K0: embed e = (X@W^T)*mask_coarse ; out = bias
// 256 blocks x 256 thr; block = 8 o-rows x 128 t, k-chunked LDS tiling.
// X staged COALESCED. (r14-verified)
__global__ __launch_bounds__(256) void prep_kernel(
    const float* __restrict__ X, const float* __restrict__ W_embed,
    const float* __restrict__ mask_coarse, const float* __restrict__ b_out,
    float* __restrict__ ws, float* __restrict__ out)
{
  __shared__ float Xl[128][36];   // 128 t x 32 k chunk (pad 36)
  __shared__ float Wl[8][36];     // 8 o x 32 k chunk

  const int tid = threadIdx.x, bid = blockIdx.x;  // grid = 256
  float* eb = ws + E_OFF;

  // out = bias (scan_kernel atomicAdds channel contributions on top)
  {
    int idx = bid * 512 + tid * 2;                // 131072 = out_size
    out[idx]     = b_out[(idx >> 6) & 15];
    out[idx + 1] = b_out[((idx + 1) >> 6) & 15];
  }

  const int o0 = bid * 8;
  const int ol = tid & 7;          // o-local 0..7
  const int tg = tid >> 3;         // t-group 0..31 (4 t each)
  float acc[4] = {0.f, 0.f, 0.f, 0.f};

  for (int k0 = 0; k0 < 512; k0 += 32) {
    __syncthreads();  // protect Xl/Wl against reuse from previous chunk
#pragma unroll
    for (int p = 0; p < 4; ++p) {
      int tr = p * 32 + (tid >> 3);
      int kc = (tid & 7) * 4;
      *(float4*)&Xl[tr][kc] = *(const float4*)&X[(size_t)tr * 512 + k0 + kc];
    }
    if (tid < 64) {
      int wr = tid >> 3, wc = (tid & 7) * 4;
      *(float4*)&Wl[wr][wc] = *(const float4*)&W_embed[(size_t)(o0 + wr) * 512 + k0 + wc];
    }
    __syncthreads();
#pragma unroll
    for (int kk = 0; kk < 8; ++kk) {
      float4 w4 = *(const float4*)&Wl[ol][kk * 4];
#pragma unroll
      for (int i = 0; i < 4; ++i) {
        float4 x4 = *(const float4*)&Xl[tg * 4 + i][kk * 4];
        acc[i] = fmaf(w4.x, x4.x, fmaf(w4.y, x4.y, fmaf(w4.z, x4.z, fmaf(w4.w, x4.w, acc[i]))));
      }
    }
  }
  const int o = o0 + ol;
  float mc = mask_coarse[o & 255];
#pragma unroll
  for (int i = 0; i < 4; ++i)
    eb[(size_t)(tg * 4 + i) * 2048 + o] = acc[i] * mc;
}

// ---------------- K1: persistent scan. 256 blocks x 512 threads. (r13-exact)
// 8 ch x (4x8 tiles of 64x32). Double-buffered LDS state, ONE barrier/step.
// Exchange: packed 16B sc0sc1 payload + per-wave release tags.
__global__ __launch_bounds__(512, 2) void scan_kernel(
    const float* __restrict__ mask_fine, const float* __restrict__ W_deconv,
    const float* __restrict__ w1, const float* __restrict__ w2,
    const float* __restrict__ w_out, float* __restrict__ ws,
    float* __restrict__ out)
{
  __shared__ float zin[2][72 * 44];     // Z parity buffers, tile + 4-halo
  __shared__ float rowbuf[2][64 * 17];  // readout partials, parity

  const int tid  = threadIdx.x;       // 0..511
  const int bid  = blockIdx.x;
  const int ch   = bid >> 5;
  const int tile = bid & 31;
  const int tI = tile >> 3, tJ = tile & 7;
  const int r0 = tI << 6, c0 = tJ << 5;
  const int row = tid >> 3;           // 0..63
  const int cg  = tid & 7;
  const int lc  = cg << 2;

  float* Zb = ws + SB_OFF;
  const float* eb = ws + E_OFF;
  const int myoff = (ch * 32 + tile) << 10;   // record stride 1024

  // ---- per-thread fixed constants
  const int i0 = (r0 + row) >> 4;
  const int jj = (c0 + lc) >> 4;
  float4 wd[8];
#pragma unroll
  for (int c = 0; c < 8; ++c)
    wd[c] = *(const float4*)&W_deconv[(((c * 8 + ch) * 16) + (row & 15)) * 16 + (lc & 15)];
  float4 mf = *(const float4*)&mask_fine[(size_t)(r0 + row) * 256 + c0 + lc];
  float4 wo[16];
#pragma unroll
  for (int oc = 0; oc < 16; ++oc)
    wo[oc] = *(const float4*)&w_out[(((oc * 8 + ch) * 32) + (row & 31)) * 32 + lc];
  float w1s[9], w2s[25];
#pragma unroll
  for (int k = 0; k < 9; ++k)
    w1s[k] = __uint_as_float(__builtin_amdgcn_readfirstlane(__float_as_uint(w1[ch * 9 + k])));
#pragma unroll
  for (int k = 0; k < 25; ++k)
    w2s[k] = __uint_as_float(__builtin_amdgcn_readfirstlane(__float_as_uint(w2[ch * 25 + k])));

  // ---- fixed halo-read assignment: 208 f4 chunks; 1 per thread (tid<208)
  int rd_src = 0, rd_dst = 0, rd_tag = 0;
  const bool hasrd = (tid < 208);
  if (hasrd) {
    int u = tid, di = 0, dj = 0, src = 0, dst = 0, wv = 0;
    if (u < 32) {              // top rows 0..3 <- U.HB (U wave 7)
      di = -1; src = 128 + (u >> 3) * 32 + (u & 7) * 4;
      dst = (u >> 3) * 44 + 4 + (u & 7) * 4; wv = 7;
    } else if (u < 64) {       // bottom rows 68..71 <- D.HT (D wave 0)
      int v = u - 32; di = 1; src = (v >> 3) * 32 + (v & 7) * 4;
      dst = (68 + (v >> 3)) * 44 + 4 + (v & 7) * 4; wv = 0;
    } else if (u < 128) {      // left rows 4..67 <- L.VR (L wave v/8)
      int v = u - 64; dj = -1; src = 512 + v * 4; dst = (4 + v) * 44; wv = v >> 3;
    } else if (u < 192) {      // right rows 4..67 <- R.VL (R wave v/8)
      int v = u - 128; dj = 1; src = 256 + v * 4; dst = (4 + v) * 44 + 36; wv = v >> 3;
    } else {                   // corners, 4 chunks each
      int v = u - 192, c = v >> 2, r = v & 3;
      if (c == 0)      { di = -1; dj = -1; src = 816 + r * 4; dst = r * 44;            wv = 7; }
      else if (c == 1) { di = -1; dj = 1;  src = 800 + r * 4; dst = r * 44 + 36;       wv = 7; }
      else if (c == 2) { di = 1;  dj = -1; src = 784 + r * 4; dst = (68 + r) * 44;     wv = 0; }
      else             { di = 1;  dj = 1;  src = 768 + r * 4; dst = (68 + r) * 44 + 36; wv = 0; }
    }
    int nI = (tI + di) & 3, nJ = (tJ + dj) & 7;
    int roff = (ch * 32 + nI * 8 + nJ) << 10;
    rd_src = roff + src;
    rd_tag = roff + 832 + wv * 16;
    rd_dst = dst;
  }

  // init both parity buffers (Z0 = 0, incl. halo)
  for (int k = tid; k < 2 * 72 * 44; k += 512) zin[0][k] = 0.f;
  __syncthreads();

  for (int t = 0; t < 128; ++t) {
    float* sb = Zb + (size_t)((t + 1) & 1) * 262144;   // records for Z_{t+1}
    const float* zr = zin[t & 1];
    float*       zw = zin[(t + 1) & 1];
    float*       rb = rowbuf[t & 1];

    // input-path e values (read-only, L2-resident)
    float ev[8];
#pragma unroll
    for (int c = 0; c < 8; ++c)
      ev[c] = eb[(size_t)t * 2048 + c * 256 + i0 * 16 + jj];

    // ---- compute Z_{t+1} for this thread's 4 px (reads zr = Z_t incl halo)
    float c1a[4] = {0, 0, 0, 0}, c2a[4] = {0, 0, 0, 0};
    {
      float w[12];
      auto load_row = [&](int zrr) {
        float4 A  = *(const float4*)&zr[zrr * 44 + lc];
        float4 B  = *(const float4*)&zr[zrr * 44 + lc + 4];
        float4 Cq = *(const float4*)&zr[zrr * 44 + lc + 8];
        w[0]=A.x; w[1]=A.y; w[2]=A.z; w[3]=A.w;
        w[4]=B.x; w[5]=B.y; w[6]=B.z; w[7]=B.w;
        w[8]=Cq.x; w[9]=Cq.y; w[10]=Cq.z; w[11]=Cq.w;
      };
      auto k2row = [&](int a) {
#pragma unroll
        for (int j = 0; j < 4; ++j)
#pragma unroll
          for (int b = 0; b < 5; ++b)
            c2a[j] = fmaf(w[j + 2 * b], w2s[a * 5 + b], c2a[j]);
      };
      auto k1row = [&](int a) {
#pragma unroll
        for (int j = 0; j < 4; ++j)
#pragma unroll
          for (int b = 0; b < 3; ++b)
            c1a[j] = fmaf(w[j + 3 + b], w1s[a * 3 + b], c1a[j]);
      };
      load_row(row + 0); k2row(0);
      load_row(row + 2); k2row(1);
      load_row(row + 3); k1row(0);
      load_row(row + 4); k1row(1); k2row(2);
      load_row(row + 5); k1row(2);
      load_row(row + 6); k2row(3);
      load_row(row + 8); k2row(4);
    }
    float zv[4];
    {
      const float* mfp = (const float*)&mf;
#pragma unroll
      for (int j = 0; j < 4; ++j) {
        float u = 0.f;
#pragma unroll
        for (int c = 0; c < 8; ++c)
          u = fmaf(ev[c], ((const float*)&wd[c])[j], u);
        float val = fmaf(0.9f, c1a[j], fmaf(0.1f, c2a[j], mfp[j] * u));
        zv[j] = fast_tanh(val);
      }
    }

    // ---- publish packed 16B boundary chunks, then per-wave release tag
    if (t < 127) {
      float* rec = sb + myoff;
      if (row < 4)   st16(rec + row * 32 + lc, zv[0], zv[1], zv[2], zv[3]);            // HT
      if (row >= 60) st16(rec + 128 + (row - 60) * 32 + lc, zv[0], zv[1], zv[2], zv[3]); // HB
      if (lc == 0)   st16(rec + 256 + row * 4, zv[0], zv[1], zv[2], zv[3]);            // VL
      if (lc == 28)  st16(rec + 512 + row * 4, zv[0], zv[1], zv[2], zv[3]);            // VR
      if (row < 4 && lc == 0)   st16(rec + 768 + row * 4, zv[0], zv[1], zv[2], zv[3]); // CTL
      if (row < 4 && lc == 28)  st16(rec + 784 + row * 4, zv[0], zv[1], zv[2], zv[3]); // CTR
      if (row >= 60 && lc == 0) st16(rec + 800 + (row - 60) * 4, zv[0], zv[1], zv[2], zv[3]); // CBL
      if (row >= 60 && lc == 28) st16(rec + 816 + (row - 60) * 4, zv[0], zv[1], zv[2], zv[3]); // CBR
      if ((tid & 63) == 0)
        tag_store((unsigned*)(rec + 832 + (tid >> 6) * 16), (unsigned)(t + 1));
    }

    // ---- commit interior into the OTHER parity buffer
    *(float4*)&zw[(4 + row) * 44 + 4 + lc] = make_float4(zv[0], zv[1], zv[2], zv[3]);

    // ---- readout FMAs + octet DPP reduce -> rowbuf[parity]
    float racc[16];
#pragma unroll
    for (int oc = 0; oc < 16; ++oc) {
      const float* wop = (const float*)&wo[oc];
      racc[oc] = fmaf(zv[0], wop[0], fmaf(zv[1], wop[1], fmaf(zv[2], wop[2], zv[3] * wop[3])));
    }
#pragma unroll
    for (int k = 0; k < 16; ++k) {
      racc[k] = dpp_add<0xB1>(racc[k]);
      racc[k] = dpp_add<0x4E>(racc[k]);
      racc[k] = dpp_add<0x141>(racc[k]);
    }
    rb[row * 17 + (cg << 1)]     = racc[cg << 1];
    rb[row * 17 + (cg << 1) + 1] = racc[(cg << 1) + 1];

    // ---- halo: poll producer-wave tag (acquire), then 16B payload load
    if (t < 127 && hasrd) {
      const unsigned tg = (unsigned)(t + 1);
      const unsigned* ta = (const unsigned*)(sb + rd_tag);
      int spins = 0;
      while (__hip_atomic_load(ta, __ATOMIC_RELAXED, __HIP_MEMORY_SCOPE_AGENT) != tg) {
        __builtin_amdgcn_s_sleep(1);
        if (++spins > (1 << 18)) break;  // fail loud (wrong), never hang
      }
      vf4 v = ld16(sb + rd_src);
      zw[rd_dst]     = v.x;
      zw[rd_dst + 1] = v.y;
      zw[rd_dst + 2] = v.z;
      zw[rd_dst + 3] = v.w;
    }

    __syncthreads();  // the ONE barrier: zw (interior+halo) + rowbuf complete

    // ---- stage 2: fold rowbuf[parity] -> atomicAdd out (bias pre-initialized)
    if (tid < 32) {
      int p = tid >> 4, oc = tid & 15;
      float s = 0.f;
#pragma unroll
      for (int r = 0; r < 32; ++r) s += rb[(p * 32 + r) * 17 + oc];
      atomicAdd(&out[t * 1024 + oc * 64 + (2 * tI + p) * 8 + tJ], s);
    }
  }
}

extern "C" void kernel_launch(void* const* d_in, const int* in_sizes, int n_in,
                              void* d_out, int out_size, void* d_ws, size_t ws_size,
                              hipStream_t stream) {
  const float* X           = (const float*)d_in[0];
  const float* W_embed     = (const float*)d_in[1];
  const float* mask_coarse = (const float*)d_in[2];
  const float* mask_fine   = (const float*)d_in[3];
  const float* W_deconv    = (const float*)d_in[4];
  const float* w1          = (const float*)d_in[5];
  const float* w2          = (const float*)d_in[6];
  const float* w_out       = (const float*)d_in[7];
  const float* b_out       = (const float*)d_in[8];
  float* ws  = (float*)d_ws;
  float* out = (float*)d_out;

  prep_kernel<<<dim3(256), dim3(256), 0, stream>>>(X, W_embed, mask_coarse, b_out, ws, out);
  scan_kernel<<<dim3(256), dim3(512), 0, stream>>>(mask_fine, W_deconv, w1, w2, w_out, ws, out);
}